// Round 4
// baseline (1839.178 us; speedup 1.0000x reference)
//
#include <hip/hip_runtime.h>
#include <math.h>

#define NXC 32768
#define NVC 16384
#define OUTWC (NXC + 64 + NVC)

static constexpr float DXf   = 1.0f/32768.0f;
static constexpr float DVf   = 16.0f/16384.0f;
static constexpr float DTf   = 1e-3f;
static constexpr float VMAXf = 8.0f;
static constexpr float INV2PI= 0.15915494309189535f;

#define PS_V 16576
#define PS_X 8256
#define PS_E 8192

// ---------------- gshape ----------------
__global__ __launch_bounds__(1024) void k_gshape(float* __restrict__ g){
  __shared__ float red[1024];
  int t = threadIdx.x;
  float s = 0.f;
  for (int i = t; i < NXC; i += 1024){
    float x = (i + 0.5f)*DXf - 0.5f;
    float xx = x*10.0f;
    float gv = expf(-0.5f*xx*xx);
    g[i] = gv; s += gv;
  }
  red[t] = s; __syncthreads();
  for (int o = 512; o > 0; o >>= 1){ if (t < o) red[t] += red[t+o]; __syncthreads(); }
  float norm = 1.0f/(red[0]*DXf);
  for (int i = t; i < NXC; i += 1024) g[i] *= norm;
}

// ---------------- V stats (fused species via grid.y) ----------------
__global__ __launch_bounds__(256) void k_vstatsf(const float* __restrict__ V0, const float* __restrict__ V1,
                                                 float* __restrict__ part){
  __shared__ float Vt[64][66];
  int sp = blockIdx.y;
  const float* V = sp ? V1 : V0;
  float Amax = sp ? 1836.0f : 1.0f;
  int blk = blockIdx.x;               // 32 blocks per species
  int chunk = NVC/32;                 // 512
  int c0b = blk*chunk;
  int tid = threadIdx.x;
  int ta = tid >> 4, tb = tid & 15;
  int a0 = ta*4, b0 = tb*4;
  float acc0[4][4]={{0}}, acc1[4][4]={{0}}, accp[4][4]={{0}}, accm[4][4]={{0}};
  float vsv[4]={0,0,0,0}, vvm[4]={0,0,0,0}, vwv[4]={0,0,0,0};
  float fm = sqrtf(Amax*INV2PI);
  for (int t0 = 0; t0 < chunk; t0 += 64){
    int c0 = c0b + t0;
    for (int i = tid; i < 64*65; i += 256){
      int r = i/65, cc = i%65;
      int c = c0 - 1 + cc;
      Vt[r][cc] = (c >= 0 && c < NVC) ? V[(size_t)r*NVC + c] : 0.f;
    }
    __syncthreads();
    for (int jj = 0; jj < 64; ++jj){
      int j = c0 + jj;
      float vs = -VMAXf + (j + 0.5f)*DVf;
      float wpj = (vs > 0.f ? vs : 0.f)*DVf;
      float wmj = (vs < 0.f ? vs : 0.f)*DVf;
      float av[4], bv[4], bm[4];
      #pragma unroll
      for (int k=0;k<4;k++){ av[k]=Vt[a0+k][jj+1]; bv[k]=Vt[b0+k][jj+1]; bm[k]=Vt[b0+k][jj]; }
      float lag = (j >= 1) ? 1.f : 0.f;
      #pragma unroll
      for (int ka=0;ka<4;ka++){
        #pragma unroll
        for (int kb=0;kb<4;kb++){
          float p = av[ka]*bv[kb];
          acc0[ka][kb] += p;
          accp[ka][kb] += p*wpj;
          accm[ka][kb] += p*wmj;
          acc1[ka][kb] += lag*av[ka]*bm[kb];
        }
      }
      if (tb == 0){
        float mv = fm*expf(-0.5f*Amax*vs*vs)*DVf;
        #pragma unroll
        for (int k=0;k<4;k++){
          vsv[k] += av[k];
          vvm[k] += av[k]*mv;
          vwv[k] += av[k]*wpj;
        }
      }
    }
    __syncthreads();
  }
  float* pb = part + (size_t)(sp*32+blk)*PS_V;
  #pragma unroll
  for (int ka=0;ka<4;ka++){
    #pragma unroll
    for (int kb=0;kb<4;kb++){
      int idx = (a0+ka)*64 + (b0+kb);
      pb[idx]        = acc0[ka][kb];
      pb[4096+idx]   = acc1[ka][kb];
      pb[8192+idx]   = accp[ka][kb];
      pb[12288+idx]  = accm[ka][kb];
    }
  }
  if (tb == 0){
    #pragma unroll
    for (int k=0;k<4;k++){
      pb[16384 + a0+k] = vsv[k];
      pb[16448 + a0+k] = vvm[k];
      pb[16512 + a0+k] = vwv[k];
    }
  }
}

// ---------------- X stats (fused) ----------------
__global__ __launch_bounds__(256) void k_xstatsf(const float* __restrict__ X0, const float* __restrict__ X1,
                                                 int pitch, const float* __restrict__ gsh, float* __restrict__ part){
  __shared__ float Xt[64][66];
  int sp = blockIdx.y;
  const float* X = sp ? X1 : X0;
  int blk = blockIdx.x;               // 64 per species
  int chunk = NXC/64;                 // 512
  int c0b = blk*chunk;
  int tid = threadIdx.x, ta = tid>>4, tb = tid&15, a0 = ta*4, b0 = tb*4;
  float accg[4][4]={{0}}, acch[4][4]={{0}};
  float axg[4]={0,0,0,0};
  for (int t0=0;t0<chunk;t0+=64){
    int c0 = c0b+t0;
    for (int i=tid;i<64*65;i+=256){
      int r=i/65, cc=i%65; int x=c0-1+cc;
      Xt[r][cc] = (x>=0 && x<NXC) ? X[(size_t)r*pitch + x] : 0.f;
    }
    __syncthreads();
    for (int jj=0;jj<64;jj++){
      int x = c0+jj;
      float av[4],bv[4],bm[4];
      #pragma unroll
      for (int k=0;k<4;k++){ av[k]=Xt[a0+k][jj+1]; bv[k]=Xt[b0+k][jj+1]; bm[k]=Xt[b0+k][jj]; }
      float lag = (x>=1)?1.f:0.f;
      #pragma unroll
      for (int ka=0;ka<4;ka++){
        #pragma unroll
        for (int kb=0;kb<4;kb++){
          accg[ka][kb] += av[ka]*bv[kb];
          acch[ka][kb] += lag*av[ka]*bm[kb];
        }
      }
      if (tb==0){
        float gw = gsh[x]*DXf;
        #pragma unroll
        for (int k=0;k<4;k++) axg[k] += av[k]*gw;
      }
    }
    __syncthreads();
  }
  float* pb = part + (size_t)(sp*64+blk)*PS_X;
  #pragma unroll
  for (int ka=0;ka<4;ka++){
    #pragma unroll
    for (int kb=0;kb<4;kb++){
      int idx = (a0+ka)*64 + (b0+kb);
      pb[idx] = accg[ka][kb];
      pb[4096+idx] = acch[ka][kb];
    }
  }
  if (tb==0){
    #pragma unroll
    for (int k=0;k<4;k++) pb[8192 + a0+k] = axg[k];
  }
}

// ---------------- E-weighted grams (fused) ----------------
__global__ __launch_bounds__(256) void k_eweightf(const float* __restrict__ X0, const float* __restrict__ X1,
                                                  int pitch, const float* __restrict__ E,
                                                  float fac0, float fac1, float* __restrict__ part){
  __shared__ float Xt[64][65];
  __shared__ float Ew[64];
  int sp = blockIdx.y;
  const float* X = sp ? X1 : X0;
  float fac = sp ? fac1 : fac0;
  int blk = blockIdx.x; int chunk = NXC/64; int c0b = blk*chunk;
  int tid = threadIdx.x, ta = tid>>4, tb = tid&15, a0 = ta*4, b0 = tb*4;
  float accp[4][4]={{0}}, accm[4][4]={{0}};
  for (int t0=0;t0<chunk;t0+=64){
    int c0 = c0b+t0;
    for (int i=tid;i<64*64;i+=256){
      int r=i>>6, cc=i&63;
      Xt[r][cc] = X[(size_t)r*pitch + c0+cc];
    }
    if (tid < 64) Ew[tid] = E[c0+tid]*fac;
    __syncthreads();
    for (int jj=0;jj<64;jj++){
      float w0 = Ew[jj];
      float wp = (w0>0.f?w0:0.f)*DXf, wm = (w0<0.f?w0:0.f)*DXf;
      float av[4],bv[4];
      #pragma unroll
      for (int k=0;k<4;k++){ av[k]=Xt[a0+k][jj]; bv[k]=Xt[b0+k][jj]; }
      #pragma unroll
      for (int ka=0;ka<4;ka++){
        #pragma unroll
        for (int kb=0;kb<4;kb++){
          float p = av[ka]*bv[kb];
          accp[ka][kb] += p*wp;
          accm[ka][kb] += p*wm;
        }
      }
    }
    __syncthreads();
  }
  float* pb = part + (size_t)(sp*64+blk)*PS_E;
  #pragma unroll
  for (int ka=0;ka<4;ka++){
    #pragma unroll
    for (int kb=0;kb<4;kb++){
      int idx = (a0+ka)*64 + (b0+kb);
      pb[idx] = accp[ka][kb];
      pb[4096+idx] = accm[ka][kb];
    }
  }
}

// ---------------- reductions (fused species via grid.y) ----------------
__global__ __launch_bounds__(256) void k_reduce32f(const float* __restrict__ part, int nb, int ps,
                                                   float* __restrict__ dst){
  int sp = blockIdx.y;
  int i = blockIdx.x*256 + threadIdx.x;
  if (i < ps){
    float s = 0.f;
    for (int b=0;b<nb;b++) s += part[(size_t)(sp*nb+b)*ps + i];
    dst[(size_t)sp*ps + i] = s;
  }
}
__global__ __launch_bounds__(256) void k_reduce64f(const double* __restrict__ part, int nb,
                                                   double* __restrict__ dst){
  int sp = blockIdx.y;
  int i = blockIdx.x*256 + threadIdx.x;
  if (i < 4096){
    double s = 0.0;
    for (int b=0;b<nb;b++) s += part[(size_t)(sp*nb+b)*4096 + i];
    dst[(size_t)sp*4096 + i] = s;
  }
}

// ---------------- prep kernels ----------------
__global__ __launch_bounds__(256) void k_prep1(
  const float* __restrict__ Ve, const float* __restrict__ Vi,
  const float* __restrict__ Se, const float* __restrict__ Si, const float* __restrict__ Xi,
  const float* __restrict__ VDe, const float* __restrict__ VDi,
  float* __restrict__ Vle, float* __restrict__ Vre, float* __restrict__ Vli, float* __restrict__ Vri,
  float* __restrict__ ae, float* __restrict__ ai, float* __restrict__ fluxg)
{
  int t = threadIdx.x;
  const float* g0e = VDe; const float* g1e = VDe+4096;
  const float* g0i = VDi; const float* g1i = VDi+4096;
  const float* sVe = VDe+16384; const float* sVi = VDi+16384;
  const float* wvi = VDi+16512;
  for (int i=t;i<4096;i+=256){
    int a=i>>6, b=i&63;
    float v0a=Ve[(size_t)a*NVC], v0b=Ve[(size_t)b*NVC];
    float vea=Ve[(size_t)a*NVC+NVC-1], veb=Ve[(size_t)b*NVC+NVC-1];
    Vle[i] = (g0e[i] - v0a*v0b) - g1e[i];
    Vre[i] = g1e[b*64+a] - g0e[i] + vea*veb;
    float w0a=Vi[(size_t)a*NVC], w0b=Vi[(size_t)b*NVC];
    float wea=Vi[(size_t)a*NVC+NVC-1], web=Vi[(size_t)b*NVC+NVC-1];
    Vli[i] = (g0i[i] - w0a*w0b) - g1i[i];
    Vri[i] = g1i[b*64+a] - g0i[i] + wea*web;
  }
  __shared__ float red[64];
  if (t < 64){
    float s1=0.f,s2=0.f,tr=0.f;
    for (int q=0;q<64;q++){
      s1 += Se[t*64+q]*sVe[q];
      s2 += Si[t*64+q]*sVi[q];
      tr += Xi[(size_t)q*NXC + (NXC-1)]*Si[q*64+t];
    }
    ae[t]=s1; ai[t]=s2; red[t]=tr*wvi[t];
  }
  __syncthreads();
  if (t==0){ float s=0.f; for (int r=0;r<64;r++) s+=red[r]; fluxg[0]=s; }
}

__global__ __launch_bounds__(256) void k_prep2(const float* __restrict__ Sce, const float* __restrict__ Sci,
    const float* __restrict__ VDe, const float* __restrict__ VDi, const float* __restrict__ XiN,
    float* __restrict__ ae, float* __restrict__ ai, float* __restrict__ fluxg)
{
  const float* sVe = VDe+16384; const float* sVi = VDi+16384; const float* wvi = VDi+16512;
  __shared__ float red[64];
  int t=threadIdx.x;
  if (t<64){
    float s1=0.f,s2=0.f,tr=0.f;
    for (int q=0;q<64;q++){
      s1 += Sce[t*64+q]*sVe[q];
      s2 += Sci[t*64+q]*sVi[q];
      tr += XiN[(size_t)q*OUTWC + (NXC-1)]*Sci[q*64+t];
    }
    ae[t]=s1; ai[t]=s2; red[t]=tr*wvi[t];
  }
  __syncthreads();
  if (t==0){ float s=0.f; for(int r=0;r<64;r++) s+=red[r]; fluxg[1]=s; }
}

__global__ __launch_bounds__(256) void k_prep3(const float* __restrict__ S2e, const float* __restrict__ S2i,
    const float* __restrict__ VDe, const float* __restrict__ VDi, const float* __restrict__ XiN,
    const float* __restrict__ XDe, const float* __restrict__ XDi,
    float* __restrict__ ae, float* __restrict__ ai,
    float* __restrict__ Xnge, float* __restrict__ Xngi, float* __restrict__ fluxg)
{
  const float* sVe = VDe+16384; const float* sVi = VDi+16384; const float* wvi = VDi+16512;
  const float* Ge = XDe; const float* Gi = XDi;
  const float* XGe = XDe+8192; const float* XGi = XDi+8192;
  __shared__ float red[64];
  int t=threadIdx.x;
  if (t<64){
    float s1=0.f,s2=0.f,tr=0.f;
    for (int q=0;q<64;q++){
      s1 += S2e[t*64+q]*sVe[q];
      s2 += S2i[t*64+q]*sVi[q];
      tr += XiN[(size_t)q*OUTWC + (NXC-1)]*S2i[q*64+t];
    }
    ae[t]=s1; ai[t]=s2; red[t]=tr*wvi[t];
  }
  __syncthreads();
  if (t==0){ float s=0.f; for(int r=0;r<64;r++) s+=red[r]; fluxg[2]=s; }
  __syncthreads();
  if (t<64){
    float y1=0.f,y2=0.f;
    for (int q=0;q<64;q++){ y1 += Ge[t*64+q]*ae[q]; y2 += Gi[t*64+q]*ai[q]; }
    float f3 = fluxg[2];
    Xnge[t] = 1.0f *DXf*DVf*y1 + f3*XGe[t];
    Xngi[t] = 0.04f*DXf*DVf*y2 + f3*XGi[t];
  }
}

// ---------------- rho ----------------
__global__ __launch_bounds__(256) void k_rho(const float* __restrict__ Xe, int pe,
                                             const float* __restrict__ Xi, int pi,
                                             const float* __restrict__ ae, const float* __restrict__ ai,
                                             float* __restrict__ rho){
  int x = blockIdx.x*256 + threadIdx.x;
  float s = 0.f;
  for (int r=0;r<64;r++) s += ai[r]*Xi[(size_t)r*pi + x] - ae[r]*Xe[(size_t)r*pe + x];
  rho[x] = DVf*s;
}

// ---------------- poisson ----------------
__global__ __launch_bounds__(1024) void k_poisson(const float* __restrict__ rho, float* __restrict__ E){
  __shared__ float wsum[16];
  __shared__ float bsum[16];
  int t = threadIdx.x;
  int base = t*32;
  float loc[32];
  float run = 0.f;
  #pragma unroll
  for (int i=0;i<32;i++){ run += rho[base+i]; loc[i]=run; }
  float v = run;
  for (int off=1; off<64; off<<=1){
    float u = __shfl_up(v, off, 64);
    if ((t&63) >= off) v += u;
  }
  int wave = t>>6;
  if ((t&63)==63) wsum[wave] = v;
  __syncthreads();
  if (t==0){
    float a=0.f;
    for (int w0=0;w0<16;w0++){ float x=wsum[w0]; wsum[w0]=a; a+=x; }
  }
  __syncthreads();
  float offset = wsum[wave] + (v - run);
  float msum = 0.f;
  #pragma unroll
  for (int i=0;i<32;i++){ float e = DXf*(offset + loc[i]); loc[i]=e; msum += e; }
  float rs = msum;
  for (int off=32; off>0; off>>=1) rs += __shfl_down(rs, off, 64);
  if ((t&63)==0) bsum[wave]=rs;
  __syncthreads();
  if (t==0){ float a=0.f; for(int w0=0;w0<16;w0++) a+=bsum[w0]; bsum[0]=a; }
  __syncthreads();
  float mean = bsum[0]/(float)NXC;
  #pragma unroll
  for (int i=0;i<32;i++) E[base+i] = loc[i]-mean;
}

// ---------------- K step (fused species) ----------------
struct KArg { const float *X, *S, *VD, *Vl, *Vr; float nu, fac; float* Kout; };
__global__ __launch_bounds__(256) void k_kstepf(KArg k0, KArg k1,
    const float* __restrict__ E, const float* __restrict__ gsh, const float* __restrict__ fluxg)
{
  KArg A = blockIdx.y ? k1 : k0;
  __shared__ float Xt[64][66];
  __shared__ float Kt[64][66];
  const float* vpm = A.VD + 8192;
  const float* vmm = A.VD + 12288;
  const float* sV  = A.VD + 16384;
  const float* VMv = A.VD + 16448;
  int x0 = blockIdx.x*64;
  int tid = threadIdx.x;
  for (int i=tid;i<64*66;i+=256){
    int r = i/66, cc = i%66;
    int x = x0 - 1 + cc;
    Xt[r][cc] = (x>=0 && x<NXC)? A.X[(size_t)r*NXC + x] : 0.f;
  }
  __syncthreads();
  for (int i=tid;i<64*66;i+=256){
    int q = i/66, cc = i%66;
    float a = 0.f;
    for (int p=0;p<64;p++) a += A.S[p*64+q]*Xt[p][cc];
    Kt[q][cc] = a;
  }
  __syncthreads();
  float fo = fluxg[0];
  const float DTDX = DTf/DXf;
  for (int i=tid;i<4096;i+=256){
    int r = i>>6, xl = i&63;
    int cc = xl+1, x = x0+xl;
    float Ex = A.fac*E[x];
    float ep = Ex>0.f?Ex:0.f, em = Ex<0.f?Ex:0.f;
    float acc=0.f, nacc=0.f;
    for (int q=0;q<64;q++){
      float kk0=Kt[q][cc], km=Kt[q][cc-1], kp=Kt[q][cc+1];
      float vp_=vpm[r*64+q], vm_=vmm[r*64+q];
      float c0 = -DTDX*(vp_ - vm_) - DTf*(ep*A.Vl[r*64+q] + em*A.Vr[r*64+q]);
      acc += c0*kk0 + DTDX*(vp_*km - vm_*kp);
      nacc += sV[q]*kk0;
    }
    float y = Kt[r][cc]*(1.f - DTf*A.nu) + acc + DTf*(nacc*DVf*A.nu + fo*gsh[x])*VMv[r];
    A.Kout[(size_t)r*NXC + x] = y;
  }
}

// ---------------- L step (fused species) ----------------
struct LArg { const float *V, *S2, *ED, *XD, *Xng; float nu, Amax; float* Lout; };
__global__ __launch_bounds__(256) void k_lstepf(LArg l0, LArg l1)
{
  LArg A = blockIdx.y ? l1 : l0;
  __shared__ float Vt[64][66];
  __shared__ float Lt[64][66];
  const float* Ep = A.ED; const float* Em = A.ED+4096;
  const float* G = A.XD; const float* H = A.XD+4096;
  int v0 = blockIdx.x*64;
  int tid = threadIdx.x;
  for (int i=tid;i<64*66;i+=256){
    int r=i/66, cc=i%66; int vv=v0-1+cc;
    Vt[r][cc] = (vv>=0 && vv<NVC)? A.V[(size_t)r*NVC + vv] : 0.f;
  }
  __syncthreads();
  for (int i=tid;i<64*66;i+=256){
    int r=i/66, cc=i%66;
    float a=0.f;
    for (int q=0;q<64;q++) a += A.S2[r*64+q]*Vt[q][cc];
    Lt[r][cc]=a;
  }
  __syncthreads();
  const float DTDV = DTf/DVf;
  float fm = sqrtf(A.Amax*INV2PI);
  for (int i=tid;i<4096;i+=256){
    int r=i>>6, vl=i&63;
    int cc=vl+1, vgl=v0+vl;
    float vs = -VMAXf + (vgl+0.5f)*DVf;
    float vp = vs>0.f?vs:0.f, vm = vs<0.f?vs:0.f;
    float acc=0.f;
    for (int q=0;q<64;q++){
      float l0v=Lt[q][cc], lm=Lt[q][cc-1], lp=Lt[q][cc+1];
      float g=G[r*64+q], h=H[r*64+q], ht=H[q*64+r];
      float ep=Ep[r*64+q], em=Em[r*64+q];
      float c0 = -DTf*(vp*(g-h) + vm*(ht-g) + A.nu*DXf*g) - DTDV*(ep-em);
      acc += c0*l0v + DTDV*(ep*lm - em*lp);
    }
    float mv = fm*expf(-0.5f*A.Amax*vs*vs);
    float y = Lt[r][cc] + acc + DTf*A.Xng[r]*mv;
    A.Lout[(size_t)r*NVC + vgl] = y;
  }
}

// ---------------- S step ----------------
struct SArgs {
  const float *S, *XD, *ED, *VD, *Vl, *Vr, *avec;
  float *S2;
  float nu;
};
__global__ __launch_bounds__(256) void k_sstep(SArgs ea, SArgs ia, const float* __restrict__ fluxg){
  SArgs A = (blockIdx.x==0)? ea : ia;
  const float* G = A.XD; const float* H = A.XD+4096; const float* XG = A.XD+8192;
  const float* Ep = A.ED; const float* Em = A.ED+4096;
  const float* vpm = A.VD+8192; const float* vmm = A.VD+12288; const float* VMv = A.VD+16448;
  __shared__ float Sl[64*65];
  __shared__ float Tt[64*65];
  __shared__ float ACC[64*65];
  __shared__ float xng[64];
  int tid = threadIdx.x;
  for (int i=tid;i<4096;i+=256) Sl[(i>>6)*65+(i&63)] = A.S[i];
  __syncthreads();
  for (int i=tid;i<4096;i+=256){
    int a=i>>6,b=i&63; float s=0.f;
    for (int c=0;c<64;c++) s += (G[a*64+c]-H[a*64+c])*Sl[c*65+b];
    Tt[a*65+b]=s;
  }
  __syncthreads();
  for (int i=tid;i<4096;i+=256){
    int a=i>>6,b=i&63; float s=0.f;
    for (int c=0;c<64;c++) s += Tt[a*65+c]*vpm[c*64+b];
    ACC[a*65+b]=s;
  }
  __syncthreads();
  for (int i=tid;i<4096;i+=256){
    int a=i>>6,b=i&63; float s=0.f;
    for (int c=0;c<64;c++) s += (H[c*64+a]-G[a*64+c])*Sl[c*65+b];
    Tt[a*65+b]=s;
  }
  __syncthreads();
  for (int i=tid;i<4096;i+=256){
    int a=i>>6,b=i&63; float s=0.f;
    for (int c=0;c<64;c++) s += Tt[a*65+c]*vmm[c*64+b];
    ACC[a*65+b]+=s;
  }
  __syncthreads();
  for (int i=tid;i<4096;i+=256){
    int a=i>>6,b=i&63; float s=0.f;
    for (int c=0;c<64;c++) s += Ep[a*64+c]*Sl[c*65+b];
    Tt[a*65+b]=s;
  }
  __syncthreads();
  for (int i=tid;i<4096;i+=256){
    int a=i>>6,b=i&63; float s=0.f;
    for (int c=0;c<64;c++) s += Tt[a*65+c]*A.Vl[b*64+c];
    ACC[a*65+b]+=s;
  }
  __syncthreads();
  for (int i=tid;i<4096;i+=256){
    int a=i>>6,b=i&63; float s=0.f;
    for (int c=0;c<64;c++) s += Em[a*64+c]*Sl[c*65+b];
    Tt[a*65+b]=s;
  }
  __syncthreads();
  for (int i=tid;i<4096;i+=256){
    int a=i>>6,b=i&63; float s=0.f;
    for (int c=0;c<64;c++) s += Tt[a*65+c]*A.Vr[b*64+c];
    ACC[a*65+b]+=s;
  }
  if (tid<64){
    float y=0.f;
    for (int q=0;q<64;q++) y += G[tid*64+q]*A.avec[q];
    xng[tid] = A.nu*DXf*DVf*y + fluxg[1]*XG[tid];
  }
  __syncthreads();
  for (int i=tid;i<4096;i+=256){
    int a=i>>6,b=i&63; float s=0.f;
    for (int c=0;c<64;c++) s += G[a*64+c]*Sl[c*65+b];
    float accv = ACC[a*65+b] + A.nu*DXf*s - xng[a]*VMv[b];
    A.S2[i] = A.S[i] + DTf*accv;
  }
}

// ---------------- Gram (fused, fp64 partials) ----------------
__global__ __launch_bounds__(256) void k_gramf(const float* __restrict__ A0, const float* __restrict__ A1,
                                               int n, double* __restrict__ part){
  __shared__ float At[64][65];
  int sp = blockIdx.y;
  const float* A = sp ? A1 : A0;
  int blk = blockIdx.x, nb = gridDim.x;
  int chunk = n/nb;
  int c0b = blk*chunk;
  int tid=threadIdx.x, ta=tid>>4, tb=tid&15, a0=ta*4, b0=tb*4;
  double acc[4][4];
  #pragma unroll
  for (int ka=0;ka<4;ka++){
    #pragma unroll
    for (int kb=0;kb<4;kb++) acc[ka][kb]=0.0;
  }
  for (int t0=0;t0<chunk;t0+=64){
    int c0=c0b+t0;
    for (int i=tid;i<64*64;i+=256){ int r=i>>6, cc=i&63; At[r][cc]=A[(size_t)r*n + c0+cc]; }
    __syncthreads();
    for (int cc=0;cc<64;cc++){
      float av[4],bv[4];
      #pragma unroll
      for(int k=0;k<4;k++){ av[k]=At[a0+k][cc]; bv[k]=At[b0+k][cc]; }
      #pragma unroll
      for(int ka=0;ka<4;ka++){
        #pragma unroll
        for(int kb=0;kb<4;kb++) acc[ka][kb] += (double)av[ka]*(double)bv[kb];
      }
    }
    __syncthreads();
  }
  double* pb = part + (size_t)(sp*nb+blk)*4096;
  #pragma unroll
  for(int ka=0;ka<4;ka++){
    #pragma unroll
    for(int kb=0;kb<4;kb++) pb[(a0+ka)*64 + b0+kb] = acc[ka][kb];
  }
}

// ---------------- fused QR: latency-optimized ----------------
// chol: single barrier per k (raw LDL-style update with 1/d), end-scaled by rsqrt(diag)
// inverse: wavefront-parallel back-substitution (4 threads per column)
// bottom chol: fp32 (feeds Householder signs only)
// Householder: single barrier per k (owners of col k+1 compute next pivot), double-buffered v
struct QArgs {
  const double* Gd; const float* A; int n;
  float scaleS, invQ;
  float* SolveM; float* Sout; int outPitch; int mode;
};
__global__ __launch_bounds__(256) void k_qr(QArgs q0, QArgs q1){
  QArgs Q = (blockIdx.x==0)? q0 : q1;
  __shared__ double Lg[64*65];   // fp64 Gram -> R
  __shared__ float  Lw[64*65];   // R^{-1} (upper, fp32)
  __shared__ float  Rcf[64*64];  // R (fp32)
  __shared__ float  Atf[64*65];  // top 64x64 of A
  __shared__ float  Cf[64*65];   // bottom-chol C (fp32)
  __shared__ double dsd[64];
  __shared__ float  dsf[64];
  __shared__ float  vbuf[2][132];
  __shared__ float  Dv[64];
  __shared__ float  sredb[2];
  int tid = threadIdx.x;
  for (int i=tid;i<4096;i+=256) Lg[(i>>6)*65 + (i&63)] = Q.Gd[i];
  for (int i=tid;i<4096;i+=256){ int c=i>>6,x=i&63; Atf[c*65+x] = Q.A[(size_t)c*Q.n + x]; }
  __syncthreads();
  // ---- fp64 Cholesky, 1 barrier/k ----
  for (int k=0;k<63;k++){
    double d = Lg[k*65+k];
    double rinv = 1.0/(d > 0.0 ? d : 1e-300);
    for (int i=(k+1)*64 + tid; i<4096; i+=256){
      int r=i>>6, c=i&63;
      if (c>=r) Lg[r*65+c] -= Lg[k*65+r]*Lg[k*65+c]*rinv;
    }
    __syncthreads();
  }
  if (tid<64){ double d = Lg[tid*65+tid]; dsd[tid] = 1.0/sqrt(d > 0.0 ? d : 1e-300); }
  __syncthreads();
  for (int i=tid;i<4096;i+=256){
    int r=i>>6, c=i&63;
    if (c>=r) Lg[r*65+c] *= dsd[r];       // diag -> sqrt(d)
  }
  __syncthreads();
  for (int i=tid;i<4096;i+=256){ int r=i>>6,c=i&63; Rcf[i] = (c>=r)? (float)Lg[r*65+c] : 0.f; }
  // ---- wavefront triangular inverse: Lw = R^{-1} ----
  {
    int c4 = tid>>2, l4 = tid&3;
    for (int r=63;r>=0;r--){
      double s = 0.0;
      if (c4>=r){
        for (int j=r+1+l4;j<=c4;j+=4) s += Lg[r*65+j]*(double)Lw[j*65+c4];
      }
      s += __shfl_xor(s,1,64); s += __shfl_xor(s,2,64);
      if (c4>=r && l4==0) Lw[r*65+c4] = (float)((((c4==r)?1.0:0.0)-s)/Lg[r*65+r]);
      __syncthreads();
    }
  }
  // ---- Gbot = G - Atop^T Atop -> Cf (fp32) ----
  for (int i=tid;i<4096;i+=256){
    int r=i>>6, c=i&63;
    double s = Q.Gd[i];
    for (int x=0;x<64;x++) s -= (double)Atf[r*65+x]*(double)Atf[c*65+x];
    Cf[r*65+c] = (float)s;
  }
  __syncthreads();
  // ---- fp32 Cholesky of Gbot, 1 barrier/k ----
  for (int k=0;k<63;k++){
    float d = Cf[k*65+k];
    float rinv = (d > 0.f)? 1.f/d : 0.f;
    for (int i=(k+1)*64 + tid; i<4096; i+=256){
      int r=i>>6, c=i&63;
      if (c>=r) Cf[r*65+c] -= Cf[k*65+r]*Cf[k*65+c]*rinv;
    }
    __syncthreads();
  }
  if (tid<64){ float d = Cf[tid*65+tid]; dsf[tid] = (d>0.f)? rsqrtf(d) : 0.f; }
  __syncthreads();
  for (int i=tid;i<4096;i+=256){
    int r=i>>6, c=i&63;
    if (c>=r) Cf[r*65+c] *= dsf[r];
  }
  __syncthreads();
  // ---- Householder on [Atop ; C] (128x64), 1 barrier/k ----
  int col = tid>>2, l4 = tid&3;
  int rbase = l4*32;
  float a[32];
  if (l4 < 2){
    #pragma unroll
    for (int j=0;j<32;j++) a[j] = Atf[col*65 + rbase + j];
  } else {
    #pragma unroll
    for (int j=0;j<32;j++){
      int r = rbase - 64 + j;
      a[j] = (col>=r)? Cf[r*65+col] : 0.f;
    }
  }
  if (col==0){
    float sg=0.f, al=0.f;
    #pragma unroll
    for (int j=0;j<32;j++){
      int row = rbase+j;
      sg += a[j]*a[j];
      al += (row==0)? a[j] : 0.f;
    }
    sg += __shfl_xor(sg,1,64); sg += __shfl_xor(sg,2,64);
    al += __shfl_xor(al,1,64); al += __shfl_xor(al,2,64);
    float beta = (al >= 0.f)? -sqrtf(sg) : sqrtf(sg);
    float vk = al - beta;
    if (l4==0){ Dv[0] = (beta >= 0.f)? 1.f : -1.f; sredb[0] = sg - al*beta; }
    #pragma unroll
    for (int j=0;j<32;j++){
      int row = rbase+j;
      vbuf[0][l4*33+j] = (row==0)? vk : a[j];
    }
  }
  __syncthreads();
  for (int k=0;k<63;k++){
    int sl = k&1;
    float vv = sredb[sl];
    float vj[32]; float s=0.f;
    #pragma unroll
    for (int j=0;j<32;j++){ vj[j] = vbuf[sl][l4*33+j]; s += vj[j]*a[j]; }
    s += __shfl_xor(s,1,64); s += __shfl_xor(s,2,64);
    if (col>k && vv > 0.f){
      float f = s/vv;
      #pragma unroll
      for (int j=0;j<32;j++) a[j] -= f*vj[j];
    }
    if (col==k+1){
      float sg=0.f, al=0.f;
      #pragma unroll
      for (int j=0;j<32;j++){
        int row = rbase+j;
        float v = (row>=k+1)? a[j] : 0.f;
        sg += v*v;
        al += (row==k+1)? a[j] : 0.f;
      }
      sg += __shfl_xor(sg,1,64); sg += __shfl_xor(sg,2,64);
      al += __shfl_xor(al,1,64); al += __shfl_xor(al,2,64);
      float beta = (al >= 0.f)? -sqrtf(sg) : sqrtf(sg);
      float vk = al - beta;
      if (l4==0){ Dv[k+1] = (beta >= 0.f)? 1.f : -1.f; sredb[sl^1] = sg - al*beta; }
      #pragma unroll
      for (int j=0;j<32;j++){
        int row = rbase+j;
        vbuf[sl^1][l4*33+j] = (row < k+1)? 0.f : ((row==k+1)? vk : a[j]);
      }
    }
    __syncthreads();
  }
  // ---- outputs ----
  for (int i=tid;i<4096;i+=256){
    int r=i>>6, q2=i&63;
    Q.SolveM[i] = (q2<=r)? (Dv[r]*Lw[q2*65+r]*Q.invQ) : 0.f;
    if (Q.mode==0){
      Q.Sout[i] = (q2>=r)? (Dv[r]*Rcf[r*64+q2]*Q.scaleS) : 0.f;
    } else {
      Q.Sout[(size_t)r*Q.outPitch + q2] = (r>=q2)? (Dv[q2]*Rcf[q2*64+r]*Q.scaleS) : 0.f;
    }
  }
}

// ---------------- Q formation (fused species) ----------------
__global__ __launch_bounds__(256) void k_qformf(const float* __restrict__ A0, const float* __restrict__ A1,
    int n, const float* __restrict__ M0, const float* __restrict__ M1,
    float* __restrict__ O0, float* __restrict__ O1, int pitch)
{
  int sp = blockIdx.y >> 2;
  const float* A = sp ? A1 : A0;
  const float* M = sp ? M1 : M0;
  float* Out = sp ? O1 : O0;
  int x = blockIdx.x*256 + threadIdx.x;
  int r0 = (blockIdx.y & 3)*16;
  float acc[16];
  #pragma unroll
  for (int rr=0;rr<16;rr++) acc[rr]=0.f;
  for (int q=0;q<64;q++){
    float aq = A[(size_t)q*n + x];
    #pragma unroll
    for (int rr=0;rr<16;rr++) acc[rr] += M[(r0+rr)*64 + q]*aq;
  }
  #pragma unroll
  for (int rr=0;rr<16;rr++) Out[(size_t)(r0+rr)*pitch + x] = acc[rr];
}

// ======================= host =======================
extern "C" void kernel_launch(void* const* d_in, const int* in_sizes, int n_in,
                              void* d_out, int out_size, void* d_ws, size_t ws_size,
                              hipStream_t stream)
{
  (void)in_sizes; (void)n_in; (void)out_size; (void)ws_size;
  const float* Xe = (const float*)d_in[0];
  const float* Se = (const float*)d_in[1];
  const float* Ve = (const float*)d_in[2];
  const float* Xi = (const float*)d_in[3];
  const float* Si = (const float*)d_in[4];
  const float* Vi = (const float*)d_in[5];
  float* out = (float*)d_out;
  float* w = (float*)d_ws;

  size_t o = 0;
  auto alloc = [&](size_t nn){ size_t r=o; o += (nn+63)&~(size_t)63; return r; };
  size_t F_VD = alloc(2*PS_V);
  size_t F_XD = alloc(2*PS_X);
  size_t F_ED = alloc(2*PS_E);
  size_t F_VL_E = alloc(4096), F_VR_E = alloc(4096), F_VL_I = alloc(4096), F_VR_I = alloc(4096);
  size_t F_SC_E = alloc(4096), F_SC_I = alloc(4096), F_S2_E = alloc(4096), F_S2_I = alloc(4096);
  size_t F_SOLVE_E = alloc(4096), F_SOLVE_I = alloc(4096);
  size_t F_AE = alloc(64), F_AI = alloc(64), F_XNGE = alloc(64), F_XNGI = alloc(64);
  size_t F_FLUX = alloc(64);
  size_t F_GSH = alloc(NXC);
  size_t F_RHO = alloc(NXC);
  size_t F_E   = alloc(NXC);
  size_t F_KE = alloc((size_t)64*NXC);
  size_t F_KI = alloc((size_t)64*NXC);
  size_t F_LE = F_KE;
  size_t F_LI = F_KI;
  size_t F_PART = alloc(1060864);
  size_t F_GQR = alloc(16384);   // 8192 doubles (2 species)
  double* Gqr = (double*)(w + F_GQR);
  double* partd = (double*)(w + F_PART);
  float* part = w + F_PART;
  const float* VDe = w + F_VD;
  const float* VDi = w + F_VD + PS_V;
  const float* XDe = w + F_XD;
  const float* XDi = w + F_XD + PS_X;
  const float* EDe = w + F_ED;
  const float* EDi = w + F_ED + PS_E;

  float sqDX = sqrtf(DXf), isqDX = 1.f/sqrtf(DXf);
  float sqDV = sqrtf(DVf), isqDV = 1.f/sqrtf(DVf);
  const float NUE = 1.0f, NUI = 0.04f;
  const float FACE = -1.0f, FACI = 1.0f/1836.0f;

  // --- V-derived stats ---
  k_vstatsf<<<dim3(32,2),256,0,stream>>>(Ve, Vi, part);
  k_reduce32f<<<dim3((PS_V+255)/256,2),256,0,stream>>>(part, 32, PS_V, w+F_VD);
  k_gshape<<<1,1024,0,stream>>>(w+F_GSH);
  k_prep1<<<1,256,0,stream>>>(Ve, Vi, Se, Si, Xi, VDe, VDi,
                              w+F_VL_E, w+F_VR_E, w+F_VL_I, w+F_VR_I,
                              w+F_AE, w+F_AI, w+F_FLUX);
  // --- K step ---
  k_rho<<<NXC/256,256,0,stream>>>(Xe, NXC, Xi, NXC, w+F_AE, w+F_AI, w+F_RHO);
  k_poisson<<<1,1024,0,stream>>>(w+F_RHO, w+F_E);
  KArg ke{Xe, Se, VDe, w+F_VL_E, w+F_VR_E, NUE, FACE, w+F_KE};
  KArg ki{Xi, Si, VDi, w+F_VL_I, w+F_VR_I, NUI, FACI, w+F_KI};
  k_kstepf<<<dim3(NXC/64,2),256,0,stream>>>(ke, ki, w+F_E, w+F_GSH, w+F_FLUX);
  // --- QR of K^T (both species) ---
  k_gramf<<<dim3(64,2),256,0,stream>>>(w+F_KE, w+F_KI, NXC, partd);
  k_reduce64f<<<dim3(16,2),256,0,stream>>>(partd, 64, Gqr);
  {
    QArgs qe{Gqr,        w+F_KE, NXC, sqDX, isqDX, w+F_SOLVE_E, w+F_SC_E, 0, 0};
    QArgs qi{Gqr+4096,   w+F_KI, NXC, sqDX, isqDX, w+F_SOLVE_I, w+F_SC_I, 0, 0};
    k_qr<<<2,256,0,stream>>>(qe, qi);
  }
  k_qformf<<<dim3(NXC/256,8),256,0,stream>>>(w+F_KE, w+F_KI, NXC, w+F_SOLVE_E, w+F_SOLVE_I,
                                             out, out + (size_t)64*OUTWC, OUTWC);
  // --- X stats on new X ---
  k_xstatsf<<<dim3(64,2),256,0,stream>>>(out, out + (size_t)64*OUTWC, OUTWC, w+F_GSH, part);
  k_reduce32f<<<dim3((PS_X+255)/256,2),256,0,stream>>>(part, 64, PS_X, w+F_XD);
  // --- S step ---
  k_prep2<<<1,256,0,stream>>>(w+F_SC_E, w+F_SC_I, VDe, VDi, out + (size_t)64*OUTWC,
                              w+F_AE, w+F_AI, w+F_FLUX);
  k_rho<<<NXC/256,256,0,stream>>>(out, OUTWC, out + (size_t)64*OUTWC, OUTWC, w+F_AE, w+F_AI, w+F_RHO);
  k_poisson<<<1,1024,0,stream>>>(w+F_RHO, w+F_E);
  k_eweightf<<<dim3(64,2),256,0,stream>>>(out, out + (size_t)64*OUTWC, OUTWC, w+F_E, FACE, FACI, part);
  k_reduce32f<<<dim3((PS_E+255)/256,2),256,0,stream>>>(part, 64, PS_E, w+F_ED);
  SArgs ea; ea.S=w+F_SC_E; ea.XD=XDe; ea.ED=EDe; ea.VD=VDe; ea.Vl=w+F_VL_E; ea.Vr=w+F_VR_E; ea.avec=w+F_AE; ea.S2=w+F_S2_E; ea.nu=NUE;
  SArgs ia; ia.S=w+F_SC_I; ia.XD=XDi; ia.ED=EDi; ia.VD=VDi; ia.Vl=w+F_VL_I; ia.Vr=w+F_VR_I; ia.avec=w+F_AI; ia.S2=w+F_S2_I; ia.nu=NUI;
  k_sstep<<<2,256,0,stream>>>(ea, ia, w+F_FLUX);
  // --- L step ---
  k_prep3<<<1,256,0,stream>>>(w+F_S2_E, w+F_S2_I, VDe, VDi, out + (size_t)64*OUTWC,
                              XDe, XDi, w+F_AE, w+F_AI, w+F_XNGE, w+F_XNGI, w+F_FLUX);
  k_rho<<<NXC/256,256,0,stream>>>(out, OUTWC, out + (size_t)64*OUTWC, OUTWC, w+F_AE, w+F_AI, w+F_RHO);
  k_poisson<<<1,1024,0,stream>>>(w+F_RHO, w+F_E);
  k_eweightf<<<dim3(64,2),256,0,stream>>>(out, out + (size_t)64*OUTWC, OUTWC, w+F_E, FACE, FACI, part);
  k_reduce32f<<<dim3((PS_E+255)/256,2),256,0,stream>>>(part, 64, PS_E, w+F_ED);
  LArg le{Ve, w+F_S2_E, EDe, XDe, w+F_XNGE, NUE, 1.0f,    w+F_LE};
  LArg li{Vi, w+F_S2_I, EDi, XDi, w+F_XNGI, NUI, 1836.0f, w+F_LI};
  k_lstepf<<<dim3(NVC/64,2),256,0,stream>>>(le, li);
  // --- QR of L^T (both species) ---
  k_gramf<<<dim3(32,2),256,0,stream>>>(w+F_LE, w+F_LI, NVC, partd);
  k_reduce64f<<<dim3(16,2),256,0,stream>>>(partd, 32, Gqr);
  {
    QArgs qe{Gqr,      w+F_LE, NVC, sqDV, isqDV, w+F_SOLVE_E, out + NXC,                        OUTWC, 1};
    QArgs qi{Gqr+4096, w+F_LI, NVC, sqDV, isqDV, w+F_SOLVE_I, out + (size_t)64*OUTWC + NXC,     OUTWC, 1};
    k_qr<<<2,256,0,stream>>>(qe, qi);
  }
  k_qformf<<<dim3(NVC/256,8),256,0,stream>>>(w+F_LE, w+F_LI, NVC, w+F_SOLVE_E, w+F_SOLVE_I,
                                             out + NXC + 64, out + (size_t)64*OUTWC + NXC + 64, OUTWC);
}

// Round 5
// 1774.029 us; speedup vs baseline: 1.0367x; 1.0367x over previous
//
#include <hip/hip_runtime.h>
#include <math.h>

#define NXC 32768
#define NVC 16384
#define OUTWC (NXC + 64 + NVC)

static constexpr float DXf   = 1.0f/32768.0f;
static constexpr float DVf   = 16.0f/16384.0f;
static constexpr float DTf   = 1e-3f;
static constexpr float VMAXf = 8.0f;
static constexpr float INV2PI= 0.15915494309189535f;

#define PS_V 16576
#define PS_X 8256
#define PS_E 8192

// ---------------- gshape ----------------
__global__ __launch_bounds__(1024) void k_gshape(float* __restrict__ g){
  __shared__ float red[1024];
  int t = threadIdx.x;
  float s = 0.f;
  for (int i = t; i < NXC; i += 1024){
    float x = (i + 0.5f)*DXf - 0.5f;
    float xx = x*10.0f;
    float gv = expf(-0.5f*xx*xx);
    g[i] = gv; s += gv;
  }
  red[t] = s; __syncthreads();
  for (int o = 512; o > 0; o >>= 1){ if (t < o) red[t] += red[t+o]; __syncthreads(); }
  float norm = 1.0f/(red[0]*DXf);
  for (int i = t; i < NXC; i += 1024) g[i] *= norm;
}

// ---------------- V stats (fused species via grid.y) ----------------
__global__ __launch_bounds__(256) void k_vstatsf(const float* __restrict__ V0, const float* __restrict__ V1,
                                                 float* __restrict__ part){
  __shared__ float Vt[64][66];
  int sp = blockIdx.y;
  const float* V = sp ? V1 : V0;
  float Amax = sp ? 1836.0f : 1.0f;
  int blk = blockIdx.x;               // 32 blocks per species
  int chunk = NVC/32;                 // 512
  int c0b = blk*chunk;
  int tid = threadIdx.x;
  int ta = tid >> 4, tb = tid & 15;
  int a0 = ta*4, b0 = tb*4;
  float acc0[4][4]={{0}}, acc1[4][4]={{0}}, accp[4][4]={{0}}, accm[4][4]={{0}};
  float vsv[4]={0,0,0,0}, vvm[4]={0,0,0,0}, vwv[4]={0,0,0,0};
  float fm = sqrtf(Amax*INV2PI);
  for (int t0 = 0; t0 < chunk; t0 += 64){
    int c0 = c0b + t0;
    for (int i = tid; i < 64*65; i += 256){
      int r = i/65, cc = i%65;
      int c = c0 - 1 + cc;
      Vt[r][cc] = (c >= 0 && c < NVC) ? V[(size_t)r*NVC + c] : 0.f;
    }
    __syncthreads();
    for (int jj = 0; jj < 64; ++jj){
      int j = c0 + jj;
      float vs = -VMAXf + (j + 0.5f)*DVf;
      float wpj = (vs > 0.f ? vs : 0.f)*DVf;
      float wmj = (vs < 0.f ? vs : 0.f)*DVf;
      float av[4], bv[4], bm[4];
      #pragma unroll
      for (int k=0;k<4;k++){ av[k]=Vt[a0+k][jj+1]; bv[k]=Vt[b0+k][jj+1]; bm[k]=Vt[b0+k][jj]; }
      float lag = (j >= 1) ? 1.f : 0.f;
      #pragma unroll
      for (int ka=0;ka<4;ka++){
        #pragma unroll
        for (int kb=0;kb<4;kb++){
          float p = av[ka]*bv[kb];
          acc0[ka][kb] += p;
          accp[ka][kb] += p*wpj;
          accm[ka][kb] += p*wmj;
          acc1[ka][kb] += lag*av[ka]*bm[kb];
        }
      }
      if (tb == 0){
        float mv = fm*expf(-0.5f*Amax*vs*vs)*DVf;
        #pragma unroll
        for (int k=0;k<4;k++){
          vsv[k] += av[k];
          vvm[k] += av[k]*mv;
          vwv[k] += av[k]*wpj;
        }
      }
    }
    __syncthreads();
  }
  float* pb = part + (size_t)(sp*32+blk)*PS_V;
  #pragma unroll
  for (int ka=0;ka<4;ka++){
    #pragma unroll
    for (int kb=0;kb<4;kb++){
      int idx = (a0+ka)*64 + (b0+kb);
      pb[idx]        = acc0[ka][kb];
      pb[4096+idx]   = acc1[ka][kb];
      pb[8192+idx]   = accp[ka][kb];
      pb[12288+idx]  = accm[ka][kb];
    }
  }
  if (tb == 0){
    #pragma unroll
    for (int k=0;k<4;k++){
      pb[16384 + a0+k] = vsv[k];
      pb[16448 + a0+k] = vvm[k];
      pb[16512 + a0+k] = vwv[k];
    }
  }
}

// ---------------- X stats (fused) ----------------
__global__ __launch_bounds__(256) void k_xstatsf(const float* __restrict__ X0, const float* __restrict__ X1,
                                                 int pitch, const float* __restrict__ gsh, float* __restrict__ part){
  __shared__ float Xt[64][66];
  int sp = blockIdx.y;
  const float* X = sp ? X1 : X0;
  int blk = blockIdx.x;               // 64 per species
  int chunk = NXC/64;                 // 512
  int c0b = blk*chunk;
  int tid = threadIdx.x, ta = tid>>4, tb = tid&15, a0 = ta*4, b0 = tb*4;
  float accg[4][4]={{0}}, acch[4][4]={{0}};
  float axg[4]={0,0,0,0};
  for (int t0=0;t0<chunk;t0+=64){
    int c0 = c0b+t0;
    for (int i=tid;i<64*65;i+=256){
      int r=i/65, cc=i%65; int x=c0-1+cc;
      Xt[r][cc] = (x>=0 && x<NXC) ? X[(size_t)r*pitch + x] : 0.f;
    }
    __syncthreads();
    for (int jj=0;jj<64;jj++){
      int x = c0+jj;
      float av[4],bv[4],bm[4];
      #pragma unroll
      for (int k=0;k<4;k++){ av[k]=Xt[a0+k][jj+1]; bv[k]=Xt[b0+k][jj+1]; bm[k]=Xt[b0+k][jj]; }
      float lag = (x>=1)?1.f:0.f;
      #pragma unroll
      for (int ka=0;ka<4;ka++){
        #pragma unroll
        for (int kb=0;kb<4;kb++){
          accg[ka][kb] += av[ka]*bv[kb];
          acch[ka][kb] += lag*av[ka]*bm[kb];
        }
      }
      if (tb==0){
        float gw = gsh[x]*DXf;
        #pragma unroll
        for (int k=0;k<4;k++) axg[k] += av[k]*gw;
      }
    }
    __syncthreads();
  }
  float* pb = part + (size_t)(sp*64+blk)*PS_X;
  #pragma unroll
  for (int ka=0;ka<4;ka++){
    #pragma unroll
    for (int kb=0;kb<4;kb++){
      int idx = (a0+ka)*64 + (b0+kb);
      pb[idx] = accg[ka][kb];
      pb[4096+idx] = acch[ka][kb];
    }
  }
  if (tb==0){
    #pragma unroll
    for (int k=0;k<4;k++) pb[8192 + a0+k] = axg[k];
  }
}

// ---------------- E-weighted grams (fused) ----------------
__global__ __launch_bounds__(256) void k_eweightf(const float* __restrict__ X0, const float* __restrict__ X1,
                                                  int pitch, const float* __restrict__ E,
                                                  float fac0, float fac1, float* __restrict__ part){
  __shared__ float Xt[64][65];
  __shared__ float Ew[64];
  int sp = blockIdx.y;
  const float* X = sp ? X1 : X0;
  float fac = sp ? fac1 : fac0;
  int blk = blockIdx.x; int chunk = NXC/64; int c0b = blk*chunk;
  int tid = threadIdx.x, ta = tid>>4, tb = tid&15, a0 = ta*4, b0 = tb*4;
  float accp[4][4]={{0}}, accm[4][4]={{0}};
  for (int t0=0;t0<chunk;t0+=64){
    int c0 = c0b+t0;
    for (int i=tid;i<64*64;i+=256){
      int r=i>>6, cc=i&63;
      Xt[r][cc] = X[(size_t)r*pitch + c0+cc];
    }
    if (tid < 64) Ew[tid] = E[c0+tid]*fac;
    __syncthreads();
    for (int jj=0;jj<64;jj++){
      float w0 = Ew[jj];
      float wp = (w0>0.f?w0:0.f)*DXf, wm = (w0<0.f?w0:0.f)*DXf;
      float av[4],bv[4];
      #pragma unroll
      for (int k=0;k<4;k++){ av[k]=Xt[a0+k][jj]; bv[k]=Xt[b0+k][jj]; }
      #pragma unroll
      for (int ka=0;ka<4;ka++){
        #pragma unroll
        for (int kb=0;kb<4;kb++){
          float p = av[ka]*bv[kb];
          accp[ka][kb] += p*wp;
          accm[ka][kb] += p*wm;
        }
      }
    }
    __syncthreads();
  }
  float* pb = part + (size_t)(sp*64+blk)*PS_E;
  #pragma unroll
  for (int ka=0;ka<4;ka++){
    #pragma unroll
    for (int kb=0;kb<4;kb++){
      int idx = (a0+ka)*64 + (b0+kb);
      pb[idx] = accp[ka][kb];
      pb[4096+idx] = accm[ka][kb];
    }
  }
}

// ---------------- reductions (fused species via grid.y) ----------------
__global__ __launch_bounds__(256) void k_reduce32f(const float* __restrict__ part, int nb, int ps,
                                                   float* __restrict__ dst){
  int sp = blockIdx.y;
  int i = blockIdx.x*256 + threadIdx.x;
  if (i < ps){
    float s = 0.f;
    for (int b=0;b<nb;b++) s += part[(size_t)(sp*nb+b)*ps + i];
    dst[(size_t)sp*ps + i] = s;
  }
}
__global__ __launch_bounds__(256) void k_reduce64f(const double* __restrict__ part, int nb,
                                                   double* __restrict__ dst){
  int sp = blockIdx.y;
  int i = blockIdx.x*256 + threadIdx.x;
  if (i < 4096){
    double s = 0.0;
    for (int b=0;b<nb;b++) s += part[(size_t)(sp*nb+b)*4096 + i];
    dst[(size_t)sp*4096 + i] = s;
  }
}

// ---------------- prep kernels ----------------
__global__ __launch_bounds__(256) void k_prep1(
  const float* __restrict__ Ve, const float* __restrict__ Vi,
  const float* __restrict__ Se, const float* __restrict__ Si, const float* __restrict__ Xi,
  const float* __restrict__ VDe, const float* __restrict__ VDi,
  float* __restrict__ Vle, float* __restrict__ Vre, float* __restrict__ Vli, float* __restrict__ Vri,
  float* __restrict__ ae, float* __restrict__ ai, float* __restrict__ fluxg)
{
  int t = threadIdx.x;
  const float* g0e = VDe; const float* g1e = VDe+4096;
  const float* g0i = VDi; const float* g1i = VDi+4096;
  const float* sVe = VDe+16384; const float* sVi = VDi+16384;
  const float* wvi = VDi+16512;
  for (int i=t;i<4096;i+=256){
    int a=i>>6, b=i&63;
    float v0a=Ve[(size_t)a*NVC], v0b=Ve[(size_t)b*NVC];
    float vea=Ve[(size_t)a*NVC+NVC-1], veb=Ve[(size_t)b*NVC+NVC-1];
    Vle[i] = (g0e[i] - v0a*v0b) - g1e[i];
    Vre[i] = g1e[b*64+a] - g0e[i] + vea*veb;
    float w0a=Vi[(size_t)a*NVC], w0b=Vi[(size_t)b*NVC];
    float wea=Vi[(size_t)a*NVC+NVC-1], web=Vi[(size_t)b*NVC+NVC-1];
    Vli[i] = (g0i[i] - w0a*w0b) - g1i[i];
    Vri[i] = g1i[b*64+a] - g0i[i] + wea*web;
  }
  __shared__ float red[64];
  if (t < 64){
    float s1=0.f,s2=0.f,tr=0.f;
    for (int q=0;q<64;q++){
      s1 += Se[t*64+q]*sVe[q];
      s2 += Si[t*64+q]*sVi[q];
      tr += Xi[(size_t)q*NXC + (NXC-1)]*Si[q*64+t];
    }
    ae[t]=s1; ai[t]=s2; red[t]=tr*wvi[t];
  }
  __syncthreads();
  if (t==0){ float s=0.f; for (int r=0;r<64;r++) s+=red[r]; fluxg[0]=s; }
}

__global__ __launch_bounds__(256) void k_prep2(const float* __restrict__ Sce, const float* __restrict__ Sci,
    const float* __restrict__ VDe, const float* __restrict__ VDi, const float* __restrict__ XiN,
    float* __restrict__ ae, float* __restrict__ ai, float* __restrict__ fluxg)
{
  const float* sVe = VDe+16384; const float* sVi = VDi+16384; const float* wvi = VDi+16512;
  __shared__ float red[64];
  int t=threadIdx.x;
  if (t<64){
    float s1=0.f,s2=0.f,tr=0.f;
    for (int q=0;q<64;q++){
      s1 += Sce[t*64+q]*sVe[q];
      s2 += Sci[t*64+q]*sVi[q];
      tr += XiN[(size_t)q*OUTWC + (NXC-1)]*Sci[q*64+t];
    }
    ae[t]=s1; ai[t]=s2; red[t]=tr*wvi[t];
  }
  __syncthreads();
  if (t==0){ float s=0.f; for(int r=0;r<64;r++) s+=red[r]; fluxg[1]=s; }
}

__global__ __launch_bounds__(256) void k_prep3(const float* __restrict__ S2e, const float* __restrict__ S2i,
    const float* __restrict__ VDe, const float* __restrict__ VDi, const float* __restrict__ XiN,
    const float* __restrict__ XDe, const float* __restrict__ XDi,
    float* __restrict__ ae, float* __restrict__ ai,
    float* __restrict__ Xnge, float* __restrict__ Xngi, float* __restrict__ fluxg)
{
  const float* sVe = VDe+16384; const float* sVi = VDi+16384; const float* wvi = VDi+16512;
  const float* Ge = XDe; const float* Gi = XDi;
  const float* XGe = XDe+8192; const float* XGi = XDi+8192;
  __shared__ float red[64];
  int t=threadIdx.x;
  if (t<64){
    float s1=0.f,s2=0.f,tr=0.f;
    for (int q=0;q<64;q++){
      s1 += S2e[t*64+q]*sVe[q];
      s2 += S2i[t*64+q]*sVi[q];
      tr += XiN[(size_t)q*OUTWC + (NXC-1)]*S2i[q*64+t];
    }
    ae[t]=s1; ai[t]=s2; red[t]=tr*wvi[t];
  }
  __syncthreads();
  if (t==0){ float s=0.f; for(int r=0;r<64;r++) s+=red[r]; fluxg[2]=s; }
  __syncthreads();
  if (t<64){
    float y1=0.f,y2=0.f;
    for (int q=0;q<64;q++){ y1 += Ge[t*64+q]*ae[q]; y2 += Gi[t*64+q]*ai[q]; }
    float f3 = fluxg[2];
    Xnge[t] = 1.0f *DXf*DVf*y1 + f3*XGe[t];
    Xngi[t] = 0.04f*DXf*DVf*y2 + f3*XGi[t];
  }
}

// ---------------- rho ----------------
__global__ __launch_bounds__(256) void k_rho(const float* __restrict__ Xe, int pe,
                                             const float* __restrict__ Xi, int pi,
                                             const float* __restrict__ ae, const float* __restrict__ ai,
                                             float* __restrict__ rho){
  int x = blockIdx.x*256 + threadIdx.x;
  float s = 0.f;
  for (int r=0;r<64;r++) s += ai[r]*Xi[(size_t)r*pi + x] - ae[r]*Xe[(size_t)r*pe + x];
  rho[x] = DVf*s;
}

// ---------------- poisson ----------------
__global__ __launch_bounds__(1024) void k_poisson(const float* __restrict__ rho, float* __restrict__ E){
  __shared__ float wsum[16];
  __shared__ float bsum[16];
  int t = threadIdx.x;
  int base = t*32;
  float loc[32];
  float run = 0.f;
  #pragma unroll
  for (int i=0;i<32;i++){ run += rho[base+i]; loc[i]=run; }
  float v = run;
  for (int off=1; off<64; off<<=1){
    float u = __shfl_up(v, off, 64);
    if ((t&63) >= off) v += u;
  }
  int wave = t>>6;
  if ((t&63)==63) wsum[wave] = v;
  __syncthreads();
  if (t==0){
    float a=0.f;
    for (int w0=0;w0<16;w0++){ float x=wsum[w0]; wsum[w0]=a; a+=x; }
  }
  __syncthreads();
  float offset = wsum[wave] + (v - run);
  float msum = 0.f;
  #pragma unroll
  for (int i=0;i<32;i++){ float e = DXf*(offset + loc[i]); loc[i]=e; msum += e; }
  float rs2 = msum;
  for (int off=32; off>0; off>>=1) rs2 += __shfl_down(rs2, off, 64);
  if ((t&63)==0) bsum[wave]=rs2;
  __syncthreads();
  if (t==0){ float a=0.f; for(int w0=0;w0<16;w0++) a+=bsum[w0]; bsum[0]=a; }
  __syncthreads();
  float mean = bsum[0]/(float)NXC;
  #pragma unroll
  for (int i=0;i<32;i++) E[base+i] = loc[i]-mean;
}

// ---------------- K step (fused species) ----------------
struct KArg { const float *X, *S, *VD, *Vl, *Vr; float nu, fac; float* Kout; };
__global__ __launch_bounds__(256) void k_kstepf(KArg k0, KArg k1,
    const float* __restrict__ E, const float* __restrict__ gsh, const float* __restrict__ fluxg)
{
  KArg A = blockIdx.y ? k1 : k0;
  __shared__ float Xt[64][66];
  __shared__ float Kt[64][66];
  const float* vpm = A.VD + 8192;
  const float* vmm = A.VD + 12288;
  const float* sV  = A.VD + 16384;
  const float* VMv = A.VD + 16448;
  int x0 = blockIdx.x*64;
  int tid = threadIdx.x;
  for (int i=tid;i<64*66;i+=256){
    int r = i/66, cc = i%66;
    int x = x0 - 1 + cc;
    Xt[r][cc] = (x>=0 && x<NXC)? A.X[(size_t)r*NXC + x] : 0.f;
  }
  __syncthreads();
  for (int i=tid;i<64*66;i+=256){
    int q = i/66, cc = i%66;
    float a = 0.f;
    for (int p=0;p<64;p++) a += A.S[p*64+q]*Xt[p][cc];
    Kt[q][cc] = a;
  }
  __syncthreads();
  float fo = fluxg[0];
  const float DTDX = DTf/DXf;
  for (int i=tid;i<4096;i+=256){
    int r = i>>6, xl = i&63;
    int cc = xl+1, x = x0+xl;
    float Ex = A.fac*E[x];
    float ep = Ex>0.f?Ex:0.f, em = Ex<0.f?Ex:0.f;
    float acc=0.f, nacc=0.f;
    for (int q=0;q<64;q++){
      float kk0=Kt[q][cc], km=Kt[q][cc-1], kp=Kt[q][cc+1];
      float vp_=vpm[r*64+q], vm_=vmm[r*64+q];
      float c0 = -DTDX*(vp_ - vm_) - DTf*(ep*A.Vl[r*64+q] + em*A.Vr[r*64+q]);
      acc += c0*kk0 + DTDX*(vp_*km - vm_*kp);
      nacc += sV[q]*kk0;
    }
    float y = Kt[r][cc]*(1.f - DTf*A.nu) + acc + DTf*(nacc*DVf*A.nu + fo*gsh[x])*VMv[r];
    A.Kout[(size_t)r*NXC + x] = y;
  }
}

// ---------------- L step (fused species) ----------------
struct LArg { const float *V, *S2, *ED, *XD, *Xng; float nu, Amax; float* Lout; };
__global__ __launch_bounds__(256) void k_lstepf(LArg l0, LArg l1)
{
  LArg A = blockIdx.y ? l1 : l0;
  __shared__ float Vt[64][66];
  __shared__ float Lt[64][66];
  const float* Ep = A.ED; const float* Em = A.ED+4096;
  const float* G = A.XD; const float* H = A.XD+4096;
  int v0 = blockIdx.x*64;
  int tid = threadIdx.x;
  for (int i=tid;i<64*66;i+=256){
    int r=i/66, cc=i%66; int vv=v0-1+cc;
    Vt[r][cc] = (vv>=0 && vv<NVC)? A.V[(size_t)r*NVC + vv] : 0.f;
  }
  __syncthreads();
  for (int i=tid;i<64*66;i+=256){
    int r=i/66, cc=i%66;
    float a=0.f;
    for (int q=0;q<64;q++) a += A.S2[r*64+q]*Vt[q][cc];
    Lt[r][cc]=a;
  }
  __syncthreads();
  const float DTDV = DTf/DVf;
  float fm = sqrtf(A.Amax*INV2PI);
  for (int i=tid;i<4096;i+=256){
    int r=i>>6, vl=i&63;
    int cc=vl+1, vgl=v0+vl;
    float vs = -VMAXf + (vgl+0.5f)*DVf;
    float vp = vs>0.f?vs:0.f, vm = vs<0.f?vs:0.f;
    float acc=0.f;
    for (int q=0;q<64;q++){
      float l0v=Lt[q][cc], lm=Lt[q][cc-1], lp=Lt[q][cc+1];
      float g=G[r*64+q], h=H[r*64+q], ht=H[q*64+r];
      float ep=Ep[r*64+q], em=Em[r*64+q];
      float c0 = -DTf*(vp*(g-h) + vm*(ht-g) + A.nu*DXf*g) - DTDV*(ep-em);
      acc += c0*l0v + DTDV*(ep*lm - em*lp);
    }
    float mv = fm*expf(-0.5f*A.Amax*vs*vs);
    float y = Lt[r][cc] + acc + DTf*A.Xng[r]*mv;
    A.Lout[(size_t)r*NVC + vgl] = y;
  }
}

// ---------------- S step ----------------
struct SArgs {
  const float *S, *XD, *ED, *VD, *Vl, *Vr, *avec;
  float *S2;
  float nu;
};
__global__ __launch_bounds__(256) void k_sstep(SArgs ea, SArgs ia, const float* __restrict__ fluxg){
  SArgs A = (blockIdx.x==0)? ea : ia;
  const float* G = A.XD; const float* H = A.XD+4096; const float* XG = A.XD+8192;
  const float* Ep = A.ED; const float* Em = A.ED+4096;
  const float* vpm = A.VD+8192; const float* vmm = A.VD+12288; const float* VMv = A.VD+16448;
  __shared__ float Sl[64*65];
  __shared__ float Tt[64*65];
  __shared__ float ACC[64*65];
  __shared__ float xng[64];
  int tid = threadIdx.x;
  for (int i=tid;i<4096;i+=256) Sl[(i>>6)*65+(i&63)] = A.S[i];
  __syncthreads();
  for (int i=tid;i<4096;i+=256){
    int a=i>>6,b=i&63; float s=0.f;
    for (int c=0;c<64;c++) s += (G[a*64+c]-H[a*64+c])*Sl[c*65+b];
    Tt[a*65+b]=s;
  }
  __syncthreads();
  for (int i=tid;i<4096;i+=256){
    int a=i>>6,b=i&63; float s=0.f;
    for (int c=0;c<64;c++) s += Tt[a*65+c]*vpm[c*64+b];
    ACC[a*65+b]=s;
  }
  __syncthreads();
  for (int i=tid;i<4096;i+=256){
    int a=i>>6,b=i&63; float s=0.f;
    for (int c=0;c<64;c++) s += (H[c*64+a]-G[a*64+c])*Sl[c*65+b];
    Tt[a*65+b]=s;
  }
  __syncthreads();
  for (int i=tid;i<4096;i+=256){
    int a=i>>6,b=i&63; float s=0.f;
    for (int c=0;c<64;c++) s += Tt[a*65+c]*vmm[c*64+b];
    ACC[a*65+b]+=s;
  }
  __syncthreads();
  for (int i=tid;i<4096;i+=256){
    int a=i>>6,b=i&63; float s=0.f;
    for (int c=0;c<64;c++) s += Ep[a*64+c]*Sl[c*65+b];
    Tt[a*65+b]=s;
  }
  __syncthreads();
  for (int i=tid;i<4096;i+=256){
    int a=i>>6,b=i&63; float s=0.f;
    for (int c=0;c<64;c++) s += Tt[a*65+c]*A.Vl[b*64+c];
    ACC[a*65+b]+=s;
  }
  __syncthreads();
  for (int i=tid;i<4096;i+=256){
    int a=i>>6,b=i&63; float s=0.f;
    for (int c=0;c<64;c++) s += Em[a*64+c]*Sl[c*65+b];
    Tt[a*65+b]=s;
  }
  __syncthreads();
  for (int i=tid;i<4096;i+=256){
    int a=i>>6,b=i&63; float s=0.f;
    for (int c=0;c<64;c++) s += Tt[a*65+c]*A.Vr[b*64+c];
    ACC[a*65+b]+=s;
  }
  if (tid<64){
    float y=0.f;
    for (int q=0;q<64;q++) y += G[tid*64+q]*A.avec[q];
    xng[tid] = A.nu*DXf*DVf*y + fluxg[1]*XG[tid];
  }
  __syncthreads();
  for (int i=tid;i<4096;i+=256){
    int a=i>>6,b=i&63; float s=0.f;
    for (int c=0;c<64;c++) s += G[a*64+c]*Sl[c*65+b];
    float accv = ACC[a*65+b] + A.nu*DXf*s - xng[a]*VMv[b];
    A.S2[i] = A.S[i] + DTf*accv;
  }
}

// ---------------- Gram (fused, fp64 partials) ----------------
__global__ __launch_bounds__(256) void k_gramf(const float* __restrict__ A0, const float* __restrict__ A1,
                                               int n, double* __restrict__ part){
  __shared__ float At[64][65];
  int sp = blockIdx.y;
  const float* A = sp ? A1 : A0;
  int blk = blockIdx.x, nb = gridDim.x;
  int chunk = n/nb;
  int c0b = blk*chunk;
  int tid=threadIdx.x, ta=tid>>4, tb=tid&15, a0=ta*4, b0=tb*4;
  double acc[4][4];
  #pragma unroll
  for (int ka=0;ka<4;ka++){
    #pragma unroll
    for (int kb=0;kb<4;kb++) acc[ka][kb]=0.0;
  }
  for (int t0=0;t0<chunk;t0+=64){
    int c0=c0b+t0;
    for (int i=tid;i<64*64;i+=256){ int r=i>>6, cc=i&63; At[r][cc]=A[(size_t)r*n + c0+cc]; }
    __syncthreads();
    for (int cc=0;cc<64;cc++){
      float av[4],bv[4];
      #pragma unroll
      for(int k=0;k<4;k++){ av[k]=At[a0+k][cc]; bv[k]=At[b0+k][cc]; }
      #pragma unroll
      for(int ka=0;ka<4;ka++){
        #pragma unroll
        for(int kb=0;kb<4;kb++) acc[ka][kb] += (double)av[ka]*(double)bv[kb];
      }
    }
    __syncthreads();
  }
  double* pb = part + (size_t)(sp*nb+blk)*4096;
  #pragma unroll
  for(int ka=0;ka<4;ka++){
    #pragma unroll
    for(int kb=0;kb<4;kb++) pb[(a0+ka)*64 + b0+kb] = acc[ka][kb];
  }
}

// ---------------- blocked Cholesky (upper, 64x64, stride-65), NB=8 ----------------
__device__ inline float  rs_(float d){ return rsqrtf(d); }
__device__ inline double rs_(double d){ return 1.0/sqrt(d); }

template<typename T>
__device__ void chol_blk(T* __restrict__ M, int tid){
  for (int p=0;p<8;p++){
    const int b=8*p;
    if (tid<64){
      T st[8];
      #pragma unroll
      for (int j=0;j<8;j++) st[j] = M[(b+j)*65 + tid];
      #pragma unroll
      for (int kk=0;kk<8;kk++){
        T q[8];
        #pragma unroll
        for (int j=0;j<8;j++) q[j] = __shfl(st[kk], b+j, 64);
        T d = q[kk];
        T rinv = (d > (T)0) ? (T)1/d : (T)0;
        T sk = st[kk];
        #pragma unroll
        for (int j=0;j<8;j++) if (j>kk) st[j] -= q[j]*sk*rinv;
        T sc = (d > (T)0) ? rs_(d) : (T)0;
        st[kk] = sk*sc;
      }
      #pragma unroll
      for (int j=0;j<8;j++) M[(b+j)*65 + tid] = st[j];
    }
    __syncthreads();
    if (b+8 < 64){
      for (int i=tid;i<4096;i+=256){
        int r=i>>6, c=i&63;
        if (r>=b+8 && c>=r){
          T s=(T)0;
          #pragma unroll
          for (int j=0;j<8;j++) s += M[(b+j)*65+r]*M[(b+j)*65+c];
          M[r*65+c] -= s;
        }
      }
    }
    __syncthreads();
  }
}

// ---------------- fused QR: blocked, latency-optimized ----------------
struct QArgs {
  const double* Gd; const float* A; int n;
  float scaleS, invQ;
  float* SolveM; float* Sout; int outPitch; int mode;
};
__global__ __launch_bounds__(256) void k_qr(QArgs q0, QArgs q1){
  QArgs Q = (blockIdx.x==0)? q0 : q1;
  __shared__ double Lg[64*65];   // fp64 Gram -> R
  __shared__ float  Lw[64*65];   // R^{-1} (upper, fp32)
  __shared__ float  Rcf[64*64];  // R (fp32)
  __shared__ float  Atf[64*65];  // top 64x64 of A
  __shared__ float  Cf[64*65];   // bottom-chol C (fp32)
  __shared__ float  Vp[8*132];   // panel reflectors (128 rows)
  __shared__ float  TmpI[448];
  __shared__ float  Dd[64], Tm[64], vvs[8], tauv[8], Dv[64];
  int tid = threadIdx.x;
  for (int i=tid;i<4096;i+=256) Lg[(i>>6)*65 + (i&63)] = Q.Gd[i];
  for (int i=tid;i<4096;i+=256){ int c=i>>6,x=i&63; Atf[c*65+x] = Q.A[(size_t)c*Q.n + x]; }
  __syncthreads();
  // ---- fp64 blocked Cholesky ----
  chol_blk<double>(Lg, tid);
  // ---- Rcf copy + Gbot = G - Atop^T Atop -> Cf ----
  for (int i=tid;i<4096;i+=256){ int r=i>>6,c=i&63; Rcf[i] = (c>=r)? (float)Lg[r*65+c] : 0.f; }
  for (int i=tid;i<4096;i+=256){
    int r=i>>6, c=i&63;
    double s = Q.Gd[i];
    for (int x=0;x<64;x++) s -= (double)Atf[r*65+x]*(double)Atf[c*65+x];
    Cf[r*65+c] = (float)s;
  }
  __syncthreads();
  // ---- fp32 blocked Cholesky of Gbot ----
  chol_blk<float>(Cf, tid);
  // ---- blocked triangular inverse: Lw = Rcf^{-1} (fp32) ----
  if (tid<64){
    int p=tid>>3, cc=tid&7, b=8*p;
    float wcol[8];
    #pragma unroll
    for (int r=7;r>=0;r--){
      float s = (r==cc)? 1.f : 0.f;
      #pragma unroll
      for (int j=0;j<8;j++) if (j>r) s -= Rcf[(b+r)*64 + (b+j)]*wcol[j];
      float dg = Rcf[(b+r)*64 + (b+r)];
      wcol[r] = (r<=cc && dg!=0.f)? s/dg : 0.f;
    }
    #pragma unroll
    for (int r=0;r<8;r++) Lw[(b+r)*65 + (b+cc)] = wcol[r];
  }
  __syncthreads();
  for (int d=1; d<8; d++){
    int nb2 = 8-d;
    for (int i=tid;i<nb2*64;i+=256){
      int bb=i>>6, rc=i&63, r=rc>>3, c=rc&7;
      int p=bb, qb=p+d;
      float s=0.f;
      for (int m=p+1;m<=qb;m++){
        #pragma unroll
        for (int jj=0;jj<8;jj++)
          s += Rcf[(8*p+r)*64 + 8*m+jj]*Lw[(8*m+jj)*65 + 8*qb+c];
      }
      TmpI[i]=s;
    }
    __syncthreads();
    for (int i=tid;i<nb2*64;i+=256){
      int bb=i>>6, rc=i&63, r=rc>>3, c=rc&7;
      int p=bb, qb=p+d;
      float s=0.f;
      #pragma unroll
      for (int rr=0;rr<8;rr++)
        s += Lw[(8*p+r)*65 + 8*p+rr]*TmpI[(bb<<6)+(rr<<3)+c];
      Lw[(8*p+r)*65 + 8*qb+c] = -s;
    }
    __syncthreads();
  }
  // ---- blocked Householder on [Atop ; C] (128x64), compact-WY, NB=8 ----
  int col = tid>>2, l4 = tid&3;
  int rbase = l4*32;
  float a[32];
  if (l4 < 2){
    #pragma unroll
    for (int j=0;j<32;j++) a[j] = Atf[col*65 + rbase + j];
  } else {
    #pragma unroll
    for (int j=0;j<32;j++){
      int r = rbase - 64 + j;
      a[j] = (col>=r)? Cf[r*65+col] : 0.f;
    }
  }
  for (int p8=0;p8<8;p8++){
    const int b = 8*p8;
    // Phase A: in-panel factorization (32 consecutive lanes, shuffle-only)
    if (col>=b && col<b+8){
      #pragma unroll 1
      for (int kk=0;kk<8;kk++){
        int k = b+kk;
        float sg=0.f, al=0.f;
        #pragma unroll
        for (int j=0;j<32;j++){
          int row = rbase+j;
          float v = (row>=k)? a[j] : 0.f;
          sg += v*v;
          al += (row==k)? a[j] : 0.f;
        }
        sg += __shfl_xor(sg,1,32); sg += __shfl_xor(sg,2,32);
        al += __shfl_xor(al,1,32); al += __shfl_xor(al,2,32);
        float sgb = __shfl(sg, 4*kk, 32);
        float alb = __shfl(al, 4*kk, 32);
        float beta = (alb>=0.f)? -sqrtf(sgb) : sqrtf(sgb);
        float vk = alb - beta;
        float vv = sgb - alb*beta;
        if (col==k){
          #pragma unroll
          for (int j=0;j<32;j++){
            int row = rbase+j;
            a[j] = (row<k)? 0.f : ((row==k)? vk : a[j]);
          }
          #pragma unroll
          for (int j=0;j<32;j++) Vp[kk*132 + rbase + j] = a[j];
          if (l4==0){ Dv[k] = (beta>=0.f)? 1.f : -1.f; vvs[kk] = vv; }
        }
        float s=0.f;
        float vj[32];
        #pragma unroll
        for (int j=0;j<32;j++){ vj[j] = __shfl(a[j], 4*kk + l4, 32); s += vj[j]*a[j]; }
        s += __shfl_xor(s,1,32); s += __shfl_xor(s,2,32);
        if (col>k && vv > 0.f){
          float f = s/vv;
          #pragma unroll
          for (int j=0;j<32;j++) a[j] -= f*vj[j];
        }
      }
    }
    __syncthreads();
    // B1: pairwise reflector dots + tau
    {
      int pr = tid>>2, m = pr>>3, i2 = pr&7;
      float sd=0.f;
      #pragma unroll
      for (int j=0;j<32;j++) sd += Vp[m*132+rbase+j]*Vp[i2*132+rbase+j];
      sd += __shfl_xor(sd,1,64); sd += __shfl_xor(sd,2,64);
      if (l4==0 && m<i2) Dd[m*8+i2]=sd;
      if (tid<8) tauv[tid] = (vvs[tid]>0.f)? 1.f/vvs[tid] : 0.f;
    }
    __syncthreads();
    // B2: build T (row j owned by thread j)
    if (tid<8){
      int j=tid;
      for (int i2=0;i2<8;i2++){
        if (i2==j) Tm[j*8+j]=tauv[j];
        else if (i2>j){
          float s2=0.f;
          for (int m=j;m<i2;m++) s2 += Tm[j*8+m]*Dd[m*8+i2];
          Tm[j*8+i2] = -tauv[i2]*s2;
        } else Tm[j*8+i2]=0.f;
      }
    }
    __syncthreads();
    // B3: block-apply to trailing columns: a -= V (T^T (V^T a))
    if (col >= b+8){
      float z[8];
      #pragma unroll
      for (int kk=0;kk<8;kk++){
        float s2=0.f;
        #pragma unroll
        for (int j=0;j<32;j++) s2 += Vp[kk*132+rbase+j]*a[j];
        s2 += __shfl_xor(s2,1,64); s2 += __shfl_xor(s2,2,64);
        z[kk]=s2;
      }
      float y[8];
      #pragma unroll
      for (int kk=0;kk<8;kk++){
        float s2=0.f;
        #pragma unroll
        for (int m=0;m<8;m++) if (m<=kk) s2 += Tm[m*8+kk]*z[m];
        y[kk]=s2;
      }
      #pragma unroll
      for (int j=0;j<32;j++){
        float s2=0.f;
        #pragma unroll
        for (int kk=0;kk<8;kk++) s2 += Vp[kk*132+rbase+j]*y[kk];
        a[j] -= s2;
      }
    }
    __syncthreads();
  }
  // ---- outputs ----
  for (int i=tid;i<4096;i+=256){
    int r=i>>6, q2=i&63;
    Q.SolveM[i] = (q2<=r)? (Dv[r]*Lw[q2*65+r]*Q.invQ) : 0.f;
    if (Q.mode==0){
      Q.Sout[i] = (q2>=r)? (Dv[r]*Rcf[r*64+q2]*Q.scaleS) : 0.f;
    } else {
      Q.Sout[(size_t)r*Q.outPitch + q2] = (r>=q2)? (Dv[q2]*Rcf[q2*64+r]*Q.scaleS) : 0.f;
    }
  }
}

// ---------------- Q formation (fused species) ----------------
__global__ __launch_bounds__(256) void k_qformf(const float* __restrict__ A0, const float* __restrict__ A1,
    int n, const float* __restrict__ M0, const float* __restrict__ M1,
    float* __restrict__ O0, float* __restrict__ O1, int pitch)
{
  int sp = blockIdx.y >> 2;
  const float* A = sp ? A1 : A0;
  const float* M = sp ? M1 : M0;
  float* Out = sp ? O1 : O0;
  int x = blockIdx.x*256 + threadIdx.x;
  int r0 = (blockIdx.y & 3)*16;
  float acc[16];
  #pragma unroll
  for (int rr=0;rr<16;rr++) acc[rr]=0.f;
  for (int q=0;q<64;q++){
    float aq = A[(size_t)q*n + x];
    #pragma unroll
    for (int rr=0;rr<16;rr++) acc[rr] += M[(r0+rr)*64 + q]*aq;
  }
  #pragma unroll
  for (int rr=0;rr<16;rr++) Out[(size_t)(r0+rr)*pitch + x] = acc[rr];
}

// ======================= host =======================
extern "C" void kernel_launch(void* const* d_in, const int* in_sizes, int n_in,
                              void* d_out, int out_size, void* d_ws, size_t ws_size,
                              hipStream_t stream)
{
  (void)in_sizes; (void)n_in; (void)out_size; (void)ws_size;
  const float* Xe = (const float*)d_in[0];
  const float* Se = (const float*)d_in[1];
  const float* Ve = (const float*)d_in[2];
  const float* Xi = (const float*)d_in[3];
  const float* Si = (const float*)d_in[4];
  const float* Vi = (const float*)d_in[5];
  float* out = (float*)d_out;
  float* w = (float*)d_ws;

  size_t o = 0;
  auto alloc = [&](size_t nn){ size_t r=o; o += (nn+63)&~(size_t)63; return r; };
  size_t F_VD = alloc(2*PS_V);
  size_t F_XD = alloc(2*PS_X);
  size_t F_ED = alloc(2*PS_E);
  size_t F_VL_E = alloc(4096), F_VR_E = alloc(4096), F_VL_I = alloc(4096), F_VR_I = alloc(4096);
  size_t F_SC_E = alloc(4096), F_SC_I = alloc(4096), F_S2_E = alloc(4096), F_S2_I = alloc(4096);
  size_t F_SOLVE_E = alloc(4096), F_SOLVE_I = alloc(4096);
  size_t F_AE = alloc(64), F_AI = alloc(64), F_XNGE = alloc(64), F_XNGI = alloc(64);
  size_t F_FLUX = alloc(64);
  size_t F_GSH = alloc(NXC);
  size_t F_RHO = alloc(NXC);
  size_t F_E   = alloc(NXC);
  size_t F_KE = alloc((size_t)64*NXC);
  size_t F_KI = alloc((size_t)64*NXC);
  size_t F_LE = F_KE;
  size_t F_LI = F_KI;
  size_t F_PART = alloc(1060864);
  size_t F_GQR = alloc(16384);   // 8192 doubles (2 species)
  double* Gqr = (double*)(w + F_GQR);
  double* partd = (double*)(w + F_PART);
  float* part = w + F_PART;
  const float* VDe = w + F_VD;
  const float* VDi = w + F_VD + PS_V;
  const float* XDe = w + F_XD;
  const float* XDi = w + F_XD + PS_X;
  const float* EDe = w + F_ED;
  const float* EDi = w + F_ED + PS_E;

  float sqDX = sqrtf(DXf), isqDX = 1.f/sqrtf(DXf);
  float sqDV = sqrtf(DVf), isqDV = 1.f/sqrtf(DVf);
  const float NUE = 1.0f, NUI = 0.04f;
  const float FACE = -1.0f, FACI = 1.0f/1836.0f;

  // --- V-derived stats ---
  k_vstatsf<<<dim3(32,2),256,0,stream>>>(Ve, Vi, part);
  k_reduce32f<<<dim3((PS_V+255)/256,2),256,0,stream>>>(part, 32, PS_V, w+F_VD);
  k_gshape<<<1,1024,0,stream>>>(w+F_GSH);
  k_prep1<<<1,256,0,stream>>>(Ve, Vi, Se, Si, Xi, VDe, VDi,
                              w+F_VL_E, w+F_VR_E, w+F_VL_I, w+F_VR_I,
                              w+F_AE, w+F_AI, w+F_FLUX);
  // --- K step ---
  k_rho<<<NXC/256,256,0,stream>>>(Xe, NXC, Xi, NXC, w+F_AE, w+F_AI, w+F_RHO);
  k_poisson<<<1,1024,0,stream>>>(w+F_RHO, w+F_E);
  KArg ke{Xe, Se, VDe, w+F_VL_E, w+F_VR_E, NUE, FACE, w+F_KE};
  KArg ki{Xi, Si, VDi, w+F_VL_I, w+F_VR_I, NUI, FACI, w+F_KI};
  k_kstepf<<<dim3(NXC/64,2),256,0,stream>>>(ke, ki, w+F_E, w+F_GSH, w+F_FLUX);
  // --- QR of K^T (both species) ---
  k_gramf<<<dim3(64,2),256,0,stream>>>(w+F_KE, w+F_KI, NXC, partd);
  k_reduce64f<<<dim3(16,2),256,0,stream>>>(partd, 64, Gqr);
  {
    QArgs qe{Gqr,        w+F_KE, NXC, sqDX, isqDX, w+F_SOLVE_E, w+F_SC_E, 0, 0};
    QArgs qi{Gqr+4096,   w+F_KI, NXC, sqDX, isqDX, w+F_SOLVE_I, w+F_SC_I, 0, 0};
    k_qr<<<2,256,0,stream>>>(qe, qi);
  }
  k_qformf<<<dim3(NXC/256,8),256,0,stream>>>(w+F_KE, w+F_KI, NXC, w+F_SOLVE_E, w+F_SOLVE_I,
                                             out, out + (size_t)64*OUTWC, OUTWC);
  // --- X stats on new X ---
  k_xstatsf<<<dim3(64,2),256,0,stream>>>(out, out + (size_t)64*OUTWC, OUTWC, w+F_GSH, part);
  k_reduce32f<<<dim3((PS_X+255)/256,2),256,0,stream>>>(part, 64, PS_X, w+F_XD);
  // --- S step ---
  k_prep2<<<1,256,0,stream>>>(w+F_SC_E, w+F_SC_I, VDe, VDi, out + (size_t)64*OUTWC,
                              w+F_AE, w+F_AI, w+F_FLUX);
  k_rho<<<NXC/256,256,0,stream>>>(out, OUTWC, out + (size_t)64*OUTWC, OUTWC, w+F_AE, w+F_AI, w+F_RHO);
  k_poisson<<<1,1024,0,stream>>>(w+F_RHO, w+F_E);
  k_eweightf<<<dim3(64,2),256,0,stream>>>(out, out + (size_t)64*OUTWC, OUTWC, w+F_E, FACE, FACI, part);
  k_reduce32f<<<dim3((PS_E+255)/256,2),256,0,stream>>>(part, 64, PS_E, w+F_ED);
  SArgs ea; ea.S=w+F_SC_E; ea.XD=XDe; ea.ED=EDe; ea.VD=VDe; ea.Vl=w+F_VL_E; ea.Vr=w+F_VR_E; ea.avec=w+F_AE; ea.S2=w+F_S2_E; ea.nu=NUE;
  SArgs ia; ia.S=w+F_SC_I; ia.XD=XDi; ia.ED=EDi; ia.VD=VDi; ia.Vl=w+F_VL_I; ia.Vr=w+F_VR_I; ia.avec=w+F_AI; ia.S2=w+F_S2_I; ia.nu=NUI;
  k_sstep<<<2,256,0,stream>>>(ea, ia, w+F_FLUX);
  // --- L step ---
  k_prep3<<<1,256,0,stream>>>(w+F_S2_E, w+F_S2_I, VDe, VDi, out + (size_t)64*OUTWC,
                              XDe, XDi, w+F_AE, w+F_AI, w+F_XNGE, w+F_XNGI, w+F_FLUX);
  k_rho<<<NXC/256,256,0,stream>>>(out, OUTWC, out + (size_t)64*OUTWC, OUTWC, w+F_AE, w+F_AI, w+F_RHO);
  k_poisson<<<1,1024,0,stream>>>(w+F_RHO, w+F_E);
  k_eweightf<<<dim3(64,2),256,0,stream>>>(out, out + (size_t)64*OUTWC, OUTWC, w+F_E, FACE, FACI, part);
  k_reduce32f<<<dim3((PS_E+255)/256,2),256,0,stream>>>(part, 64, PS_E, w+F_ED);
  LArg le{Ve, w+F_S2_E, EDe, XDe, w+F_XNGE, NUE, 1.0f,    w+F_LE};
  LArg li{Vi, w+F_S2_I, EDi, XDi, w+F_XNGI, NUI, 1836.0f, w+F_LI};
  k_lstepf<<<dim3(NVC/64,2),256,0,stream>>>(le, li);
  // --- QR of L^T (both species) ---
  k_gramf<<<dim3(32,2),256,0,stream>>>(w+F_LE, w+F_LI, NVC, partd);
  k_reduce64f<<<dim3(16,2),256,0,stream>>>(partd, 32, Gqr);
  {
    QArgs qe{Gqr,      w+F_LE, NVC, sqDV, isqDV, w+F_SOLVE_E, out + NXC,                        OUTWC, 1};
    QArgs qi{Gqr+4096, w+F_LI, NVC, sqDV, isqDV, w+F_SOLVE_I, out + (size_t)64*OUTWC + NXC,     OUTWC, 1};
    k_qr<<<2,256,0,stream>>>(qe, qi);
  }
  k_qformf<<<dim3(NVC/256,8),256,0,stream>>>(w+F_LE, w+F_LI, NVC, w+F_SOLVE_E, w+F_SOLVE_I,
                                             out + NXC + 64, out + (size_t)64*OUTWC + NXC + 64, OUTWC);
}

// Round 6
// 1481.196 us; speedup vs baseline: 1.2417x; 1.1977x over previous
//
#include <hip/hip_runtime.h>
#include <math.h>

#define NXC 32768
#define NVC 16384
#define OUTWC (NXC + 64 + NVC)

static constexpr float DXf   = 1.0f/32768.0f;
static constexpr float DVf   = 16.0f/16384.0f;
static constexpr float DTf   = 1e-3f;
static constexpr float VMAXf = 8.0f;
static constexpr float INV2PI= 0.15915494309189535f;

#define PS_V 16576
#define PS_X 8256
#define PS_E 8192

// ---------------- gshape ----------------
__global__ __launch_bounds__(1024) void k_gshape(float* __restrict__ g){
  __shared__ float red[1024];
  int t = threadIdx.x;
  float s = 0.f;
  for (int i = t; i < NXC; i += 1024){
    float x = (i + 0.5f)*DXf - 0.5f;
    float xx = x*10.0f;
    float gv = expf(-0.5f*xx*xx);
    g[i] = gv; s += gv;
  }
  red[t] = s; __syncthreads();
  for (int o = 512; o > 0; o >>= 1){ if (t < o) red[t] += red[t+o]; __syncthreads(); }
  float norm = 1.0f/(red[0]*DXf);
  for (int i = t; i < NXC; i += 1024) g[i] *= norm;
}

// ---------------- V stats (fused species via grid.y) ----------------
__global__ __launch_bounds__(256) void k_vstatsf(const float* __restrict__ V0, const float* __restrict__ V1,
                                                 float* __restrict__ part){
  __shared__ float Vt[64][66];
  int sp = blockIdx.y;
  const float* V = sp ? V1 : V0;
  float Amax = sp ? 1836.0f : 1.0f;
  int blk = blockIdx.x;               // 32 blocks per species
  int chunk = NVC/32;                 // 512
  int c0b = blk*chunk;
  int tid = threadIdx.x;
  int ta = tid >> 4, tb = tid & 15;
  int a0 = ta*4, b0 = tb*4;
  float acc0[4][4]={{0}}, acc1[4][4]={{0}}, accp[4][4]={{0}}, accm[4][4]={{0}};
  float vsv[4]={0,0,0,0}, vvm[4]={0,0,0,0}, vwv[4]={0,0,0,0};
  float fm = sqrtf(Amax*INV2PI);
  for (int t0 = 0; t0 < chunk; t0 += 64){
    int c0 = c0b + t0;
    for (int i = tid; i < 64*65; i += 256){
      int r = i/65, cc = i%65;
      int c = c0 - 1 + cc;
      Vt[r][cc] = (c >= 0 && c < NVC) ? V[(size_t)r*NVC + c] : 0.f;
    }
    __syncthreads();
    for (int jj = 0; jj < 64; ++jj){
      int j = c0 + jj;
      float vs = -VMAXf + (j + 0.5f)*DVf;
      float wpj = (vs > 0.f ? vs : 0.f)*DVf;
      float wmj = (vs < 0.f ? vs : 0.f)*DVf;
      float av[4], bv[4], bm[4];
      #pragma unroll
      for (int k=0;k<4;k++){ av[k]=Vt[a0+k][jj+1]; bv[k]=Vt[b0+k][jj+1]; bm[k]=Vt[b0+k][jj]; }
      float lag = (j >= 1) ? 1.f : 0.f;
      #pragma unroll
      for (int ka=0;ka<4;ka++){
        #pragma unroll
        for (int kb=0;kb<4;kb++){
          float p = av[ka]*bv[kb];
          acc0[ka][kb] += p;
          accp[ka][kb] += p*wpj;
          accm[ka][kb] += p*wmj;
          acc1[ka][kb] += lag*av[ka]*bm[kb];
        }
      }
      if (tb == 0){
        float mv = fm*expf(-0.5f*Amax*vs*vs)*DVf;
        #pragma unroll
        for (int k=0;k<4;k++){
          vsv[k] += av[k];
          vvm[k] += av[k]*mv;
          vwv[k] += av[k]*wpj;
        }
      }
    }
    __syncthreads();
  }
  float* pb = part + (size_t)(sp*32+blk)*PS_V;
  #pragma unroll
  for (int ka=0;ka<4;ka++){
    #pragma unroll
    for (int kb=0;kb<4;kb++){
      int idx = (a0+ka)*64 + (b0+kb);
      pb[idx]        = acc0[ka][kb];
      pb[4096+idx]   = acc1[ka][kb];
      pb[8192+idx]   = accp[ka][kb];
      pb[12288+idx]  = accm[ka][kb];
    }
  }
  if (tb == 0){
    #pragma unroll
    for (int k=0;k<4;k++){
      pb[16384 + a0+k] = vsv[k];
      pb[16448 + a0+k] = vvm[k];
      pb[16512 + a0+k] = vwv[k];
    }
  }
}

// ---------------- X stats (fused) ----------------
__global__ __launch_bounds__(256) void k_xstatsf(const float* __restrict__ X0, const float* __restrict__ X1,
                                                 int pitch, const float* __restrict__ gsh, float* __restrict__ part){
  __shared__ float Xt[64][66];
  int sp = blockIdx.y;
  const float* X = sp ? X1 : X0;
  int blk = blockIdx.x;               // 64 per species
  int chunk = NXC/64;                 // 512
  int c0b = blk*chunk;
  int tid = threadIdx.x, ta = tid>>4, tb = tid&15, a0 = ta*4, b0 = tb*4;
  float accg[4][4]={{0}}, acch[4][4]={{0}};
  float axg[4]={0,0,0,0};
  for (int t0=0;t0<chunk;t0+=64){
    int c0 = c0b+t0;
    for (int i=tid;i<64*65;i+=256){
      int r=i/65, cc=i%65; int x=c0-1+cc;
      Xt[r][cc] = (x>=0 && x<NXC) ? X[(size_t)r*pitch + x] : 0.f;
    }
    __syncthreads();
    for (int jj=0;jj<64;jj++){
      int x = c0+jj;
      float av[4],bv[4],bm[4];
      #pragma unroll
      for (int k=0;k<4;k++){ av[k]=Xt[a0+k][jj+1]; bv[k]=Xt[b0+k][jj+1]; bm[k]=Xt[b0+k][jj]; }
      float lag = (x>=1)?1.f:0.f;
      #pragma unroll
      for (int ka=0;ka<4;ka++){
        #pragma unroll
        for (int kb=0;kb<4;kb++){
          accg[ka][kb] += av[ka]*bv[kb];
          acch[ka][kb] += lag*av[ka]*bm[kb];
        }
      }
      if (tb==0){
        float gw = gsh[x]*DXf;
        #pragma unroll
        for (int k=0;k<4;k++) axg[k] += av[k]*gw;
      }
    }
    __syncthreads();
  }
  float* pb = part + (size_t)(sp*64+blk)*PS_X;
  #pragma unroll
  for (int ka=0;ka<4;ka++){
    #pragma unroll
    for (int kb=0;kb<4;kb++){
      int idx = (a0+ka)*64 + (b0+kb);
      pb[idx] = accg[ka][kb];
      pb[4096+idx] = acch[ka][kb];
    }
  }
  if (tb==0){
    #pragma unroll
    for (int k=0;k<4;k++) pb[8192 + a0+k] = axg[k];
  }
}

// ---------------- E-weighted grams (fused) ----------------
__global__ __launch_bounds__(256) void k_eweightf(const float* __restrict__ X0, const float* __restrict__ X1,
                                                  int pitch, const float* __restrict__ E,
                                                  float fac0, float fac1, float* __restrict__ part){
  __shared__ float Xt[64][65];
  __shared__ float Ew[64];
  int sp = blockIdx.y;
  const float* X = sp ? X1 : X0;
  float fac = sp ? fac1 : fac0;
  int blk = blockIdx.x; int chunk = NXC/64; int c0b = blk*chunk;
  int tid = threadIdx.x, ta = tid>>4, tb = tid&15, a0 = ta*4, b0 = tb*4;
  float accp[4][4]={{0}}, accm[4][4]={{0}};
  for (int t0=0;t0<chunk;t0+=64){
    int c0 = c0b+t0;
    for (int i=tid;i<64*64;i+=256){
      int r=i>>6, cc=i&63;
      Xt[r][cc] = X[(size_t)r*pitch + c0+cc];
    }
    if (tid < 64) Ew[tid] = E[c0+tid]*fac;
    __syncthreads();
    for (int jj=0;jj<64;jj++){
      float w0 = Ew[jj];
      float wp = (w0>0.f?w0:0.f)*DXf, wm = (w0<0.f?w0:0.f)*DXf;
      float av[4],bv[4];
      #pragma unroll
      for (int k=0;k<4;k++){ av[k]=Xt[a0+k][jj]; bv[k]=Xt[b0+k][jj]; }
      #pragma unroll
      for (int ka=0;ka<4;ka++){
        #pragma unroll
        for (int kb=0;kb<4;kb++){
          float p = av[ka]*bv[kb];
          accp[ka][kb] += p*wp;
          accm[ka][kb] += p*wm;
        }
      }
    }
    __syncthreads();
  }
  float* pb = part + (size_t)(sp*64+blk)*PS_E;
  #pragma unroll
  for (int ka=0;ka<4;ka++){
    #pragma unroll
    for (int kb=0;kb<4;kb++){
      int idx = (a0+ka)*64 + (b0+kb);
      pb[idx] = accp[ka][kb];
      pb[4096+idx] = accm[ka][kb];
    }
  }
}

// ---------------- reductions (fused species via grid.y) ----------------
__global__ __launch_bounds__(256) void k_reduce32f(const float* __restrict__ part, int nb, int ps,
                                                   float* __restrict__ dst){
  int sp = blockIdx.y;
  int i = blockIdx.x*256 + threadIdx.x;
  if (i < ps){
    float s = 0.f;
    for (int b=0;b<nb;b++) s += part[(size_t)(sp*nb+b)*ps + i];
    dst[(size_t)sp*ps + i] = s;
  }
}
__global__ __launch_bounds__(256) void k_reduce64f(const double* __restrict__ part, int nb,
                                                   double* __restrict__ dst){
  int sp = blockIdx.y;
  int i = blockIdx.x*256 + threadIdx.x;
  if (i < 4096){
    double s = 0.0;
    for (int b=0;b<nb;b++) s += part[(size_t)(sp*nb+b)*4096 + i];
    dst[(size_t)sp*4096 + i] = s;
  }
}

// ---------------- prep kernels ----------------
__global__ __launch_bounds__(256) void k_prep1(
  const float* __restrict__ Ve, const float* __restrict__ Vi,
  const float* __restrict__ Se, const float* __restrict__ Si, const float* __restrict__ Xi,
  const float* __restrict__ VDe, const float* __restrict__ VDi,
  float* __restrict__ Vle, float* __restrict__ Vre, float* __restrict__ Vli, float* __restrict__ Vri,
  float* __restrict__ ae, float* __restrict__ ai, float* __restrict__ fluxg)
{
  int t = threadIdx.x;
  const float* g0e = VDe; const float* g1e = VDe+4096;
  const float* g0i = VDi; const float* g1i = VDi+4096;
  const float* sVe = VDe+16384; const float* sVi = VDi+16384;
  const float* wvi = VDi+16512;
  for (int i=t;i<4096;i+=256){
    int a=i>>6, b=i&63;
    float v0a=Ve[(size_t)a*NVC], v0b=Ve[(size_t)b*NVC];
    float vea=Ve[(size_t)a*NVC+NVC-1], veb=Ve[(size_t)b*NVC+NVC-1];
    Vle[i] = (g0e[i] - v0a*v0b) - g1e[i];
    Vre[i] = g1e[b*64+a] - g0e[i] + vea*veb;
    float w0a=Vi[(size_t)a*NVC], w0b=Vi[(size_t)b*NVC];
    float wea=Vi[(size_t)a*NVC+NVC-1], web=Vi[(size_t)b*NVC+NVC-1];
    Vli[i] = (g0i[i] - w0a*w0b) - g1i[i];
    Vri[i] = g1i[b*64+a] - g0i[i] + wea*web;
  }
  __shared__ float red[64];
  if (t < 64){
    float s1=0.f,s2=0.f,tr=0.f;
    for (int q=0;q<64;q++){
      s1 += Se[t*64+q]*sVe[q];
      s2 += Si[t*64+q]*sVi[q];
      tr += Xi[(size_t)q*NXC + (NXC-1)]*Si[q*64+t];
    }
    ae[t]=s1; ai[t]=s2; red[t]=tr*wvi[t];
  }
  __syncthreads();
  if (t==0){ float s=0.f; for (int r=0;r<64;r++) s+=red[r]; fluxg[0]=s; }
}

__global__ __launch_bounds__(256) void k_prep2(const float* __restrict__ Sce, const float* __restrict__ Sci,
    const float* __restrict__ VDe, const float* __restrict__ VDi, const float* __restrict__ XiN,
    float* __restrict__ ae, float* __restrict__ ai, float* __restrict__ fluxg)
{
  const float* sVe = VDe+16384; const float* sVi = VDi+16384; const float* wvi = VDi+16512;
  __shared__ float red[64];
  int t=threadIdx.x;
  if (t<64){
    float s1=0.f,s2=0.f,tr=0.f;
    for (int q=0;q<64;q++){
      s1 += Sce[t*64+q]*sVe[q];
      s2 += Sci[t*64+q]*sVi[q];
      tr += XiN[(size_t)q*OUTWC + (NXC-1)]*Sci[q*64+t];
    }
    ae[t]=s1; ai[t]=s2; red[t]=tr*wvi[t];
  }
  __syncthreads();
  if (t==0){ float s=0.f; for(int r=0;r<64;r++) s+=red[r]; fluxg[1]=s; }
}

__global__ __launch_bounds__(256) void k_prep3(const float* __restrict__ S2e, const float* __restrict__ S2i,
    const float* __restrict__ VDe, const float* __restrict__ VDi, const float* __restrict__ XiN,
    const float* __restrict__ XDe, const float* __restrict__ XDi,
    float* __restrict__ ae, float* __restrict__ ai,
    float* __restrict__ Xnge, float* __restrict__ Xngi, float* __restrict__ fluxg)
{
  const float* sVe = VDe+16384; const float* sVi = VDi+16384; const float* wvi = VDi+16512;
  const float* Ge = XDe; const float* Gi = XDi;
  const float* XGe = XDe+8192; const float* XGi = XDi+8192;
  __shared__ float red[64];
  int t=threadIdx.x;
  if (t<64){
    float s1=0.f,s2=0.f,tr=0.f;
    for (int q=0;q<64;q++){
      s1 += S2e[t*64+q]*sVe[q];
      s2 += S2i[t*64+q]*sVi[q];
      tr += XiN[(size_t)q*OUTWC + (NXC-1)]*S2i[q*64+t];
    }
    ae[t]=s1; ai[t]=s2; red[t]=tr*wvi[t];
  }
  __syncthreads();
  if (t==0){ float s=0.f; for(int r=0;r<64;r++) s+=red[r]; fluxg[2]=s; }
  __syncthreads();
  if (t<64){
    float y1=0.f,y2=0.f;
    for (int q=0;q<64;q++){ y1 += Ge[t*64+q]*ae[q]; y2 += Gi[t*64+q]*ai[q]; }
    float f3 = fluxg[2];
    Xnge[t] = 1.0f *DXf*DVf*y1 + f3*XGe[t];
    Xngi[t] = 0.04f*DXf*DVf*y2 + f3*XGi[t];
  }
}

// ---------------- rho ----------------
__global__ __launch_bounds__(256) void k_rho(const float* __restrict__ Xe, int pe,
                                             const float* __restrict__ Xi, int pi,
                                             const float* __restrict__ ae, const float* __restrict__ ai,
                                             float* __restrict__ rho){
  int x = blockIdx.x*256 + threadIdx.x;
  float s = 0.f;
  for (int r=0;r<64;r++) s += ai[r]*Xi[(size_t)r*pi + x] - ae[r]*Xe[(size_t)r*pe + x];
  rho[x] = DVf*s;
}

// ---------------- poisson ----------------
__global__ __launch_bounds__(1024) void k_poisson(const float* __restrict__ rho, float* __restrict__ E){
  __shared__ float wsum[16];
  __shared__ float bsum[16];
  int t = threadIdx.x;
  int base = t*32;
  float loc[32];
  float run = 0.f;
  #pragma unroll
  for (int i=0;i<32;i++){ run += rho[base+i]; loc[i]=run; }
  float v = run;
  for (int off=1; off<64; off<<=1){
    float u = __shfl_up(v, off, 64);
    if ((t&63) >= off) v += u;
  }
  int wave = t>>6;
  if ((t&63)==63) wsum[wave] = v;
  __syncthreads();
  if (t==0){
    float a=0.f;
    for (int w0=0;w0<16;w0++){ float x=wsum[w0]; wsum[w0]=a; a+=x; }
  }
  __syncthreads();
  float offset = wsum[wave] + (v - run);
  float msum = 0.f;
  #pragma unroll
  for (int i=0;i<32;i++){ float e = DXf*(offset + loc[i]); loc[i]=e; msum += e; }
  float rs2 = msum;
  for (int off=32; off>0; off>>=1) rs2 += __shfl_down(rs2, off, 64);
  if ((t&63)==0) bsum[wave]=rs2;
  __syncthreads();
  if (t==0){ float a=0.f; for(int w0=0;w0<16;w0++) a+=bsum[w0]; bsum[0]=a; }
  __syncthreads();
  float mean = bsum[0]/(float)NXC;
  #pragma unroll
  for (int i=0;i<32;i++) E[base+i] = loc[i]-mean;
}

// ---------------- K step v2 (fused species, LDS-staged matrices, row-tiled) ----------------
#define MS(m,r,c) Mv[(m)*4160 + (r)*65 + (c)]
struct KArg { const float *X, *S, *VD, *Vl, *Vr; float nu, fac; float* Kout; };
__global__ __launch_bounds__(256) void k_kstepf(KArg k0, KArg k1,
    const float* __restrict__ E, const float* __restrict__ gsh, const float* __restrict__ fluxg)
{
  KArg A = blockIdx.y ? k1 : k0;
  __shared__ float Xt[64][66];
  __shared__ float Kt[64][66];
  __shared__ float Mv[4*4160];
  __shared__ float sVs[64], VMs[64];
  int x0 = blockIdx.x*64;
  int tid = threadIdx.x;
  for (int i=tid;i<64*66;i+=256){
    int r = i/66, cc = i%66;
    int x = x0 - 1 + cc;
    Xt[r][cc] = (x>=0 && x<NXC)? A.X[(size_t)r*NXC + x] : 0.f;
  }
  for (int i=tid;i<4096;i+=256){ MS(0, i>>6, i&63) = A.S[i]; }
  __syncthreads();
  for (int i=tid;i<64*66;i+=256){
    int q = i/66, cc = i%66;
    float a = 0.f;
    for (int p=0;p<64;p++) a += MS(0,p,q)*Xt[p][cc];
    Kt[q][cc] = a;
  }
  __syncthreads();
  {
    const float* vpm = A.VD + 8192;
    const float* vmm = A.VD + 12288;
    for (int i=tid;i<4096;i+=256){
      int r=i>>6, c=i&63;
      MS(0,r,c)=vpm[i]; MS(1,r,c)=vmm[i]; MS(2,r,c)=A.Vl[i]; MS(3,r,c)=A.Vr[i];
    }
    if (tid<64){ sVs[tid]=A.VD[16384+tid]; VMs[tid]=A.VD[16448+tid]; }
  }
  __syncthreads();
  int r = tid>>2, c4 = tid&3;
  float fo = fluxg[0];
  const float DTDX = DTf/DXf;
  float acc[16], nacc[16], epv[16], emv[16];
  #pragma unroll
  for (int c=0;c<16;c++){
    int x = x0 + c4*16 + c;
    float Ex = A.fac*E[x];
    epv[c] = Ex>0.f?Ex:0.f; emv[c] = Ex<0.f?Ex:0.f;
    acc[c]=0.f; nacc[c]=0.f;
  }
  for (int q=0;q<64;q++){
    float vp_ = MS(0,r,q), vm_ = MS(1,r,q), vl = MS(2,r,q), vr = MS(3,r,q), sq = sVs[q];
    float w0 = -DTDX*(vp_ - vm_);
    float kseg[18];
    #pragma unroll
    for (int c=0;c<18;c++) kseg[c] = Kt[q][c4*16 + c];
    #pragma unroll
    for (int c=0;c<16;c++){
      float kk0 = kseg[c+1];
      acc[c] += (w0 - DTf*(epv[c]*vl + emv[c]*vr))*kk0 + DTDX*(vp_*kseg[c] - vm_*kseg[c+2]);
      nacc[c] += sq*kk0;
    }
  }
  float vmr = VMs[r];
  #pragma unroll
  for (int c=0;c<16;c++){
    int cc = c4*16 + c + 1, x = x0 + c4*16 + c;
    float y = Kt[r][cc]*(1.f - DTf*A.nu) + acc[c] + DTf*(nacc[c]*DVf*A.nu + fo*gsh[x])*vmr;
    A.Kout[(size_t)r*NXC + x] = y;
  }
}

// ---------------- L step v2 (fused species, LDS-staged matrices, row-tiled) ----------------
struct LArg { const float *V, *S2, *ED, *XD, *Xng; float nu, Amax; float* Lout; };
__global__ __launch_bounds__(256) void k_lstepf(LArg l0, LArg l1)
{
  LArg A = blockIdx.y ? l1 : l0;
  __shared__ float Vt[64][66];
  __shared__ float Lt[64][66];
  __shared__ float Mv[4*4160];
  __shared__ float xngs[64];
  int v0 = blockIdx.x*64;
  int tid = threadIdx.x;
  for (int i=tid;i<64*66;i+=256){
    int r=i/66, cc=i%66; int vv=v0-1+cc;
    Vt[r][cc] = (vv>=0 && vv<NVC)? A.V[(size_t)r*NVC + vv] : 0.f;
  }
  for (int i=tid;i<4096;i+=256){ MS(0, i>>6, i&63) = A.S2[i]; }
  __syncthreads();
  for (int i=tid;i<64*66;i+=256){
    int r=i/66, cc=i%66;
    float a=0.f;
    for (int q=0;q<64;q++) a += MS(0,r,q)*Vt[q][cc];
    Lt[r][cc]=a;
  }
  __syncthreads();
  {
    const float* G = A.XD; const float* H = A.XD+4096;
    const float* Ep = A.ED; const float* Em = A.ED+4096;
    for (int i=tid;i<4096;i+=256){
      int r=i>>6, c=i&63;
      MS(0,r,c)=G[i]; MS(1,r,c)=H[i]; MS(2,r,c)=Ep[i]; MS(3,r,c)=Em[i];
    }
    if (tid<64) xngs[tid]=A.Xng[tid];
  }
  __syncthreads();
  int r = tid>>2, c4 = tid&3;
  const float DTDV = DTf/DVf;
  float fm = sqrtf(A.Amax*INV2PI);
  float acc[16], vpc[16], vmc[16], mvv[16];
  #pragma unroll
  for (int c=0;c<16;c++){
    int vgl = v0 + c4*16 + c;
    float vs = -VMAXf + (vgl+0.5f)*DVf;
    vpc[c] = vs>0.f?vs:0.f; vmc[c] = vs<0.f?vs:0.f;
    mvv[c] = fm*expf(-0.5f*A.Amax*vs*vs);
    acc[c] = 0.f;
  }
  for (int q=0;q<64;q++){
    float g = MS(0,r,q), h = MS(1,r,q), ht = MS(1,q,r);
    float ep = MS(2,r,q), em = MS(3,r,q);
    float base = -DTf*A.nu*DXf*g - DTDV*(ep-em);
    float lseg[18];
    #pragma unroll
    for (int c=0;c<18;c++) lseg[c] = Lt[q][c4*16 + c];
    #pragma unroll
    for (int c=0;c<16;c++){
      float c0 = base - DTf*(vpc[c]*(g-h) + vmc[c]*(ht-g));
      acc[c] += c0*lseg[c+1] + DTDV*(ep*lseg[c] - em*lseg[c+2]);
    }
  }
  float xr = xngs[r];
  #pragma unroll
  for (int c=0;c<16;c++){
    int cc = c4*16 + c + 1, vgl = v0 + c4*16 + c;
    float y = Lt[r][cc] + acc[c] + DTf*xr*mvv[c];
    A.Lout[(size_t)r*NVC + vgl] = y;
  }
}

// ---------------- S step ----------------
struct SArgs {
  const float *S, *XD, *ED, *VD, *Vl, *Vr, *avec;
  float *S2;
  float nu;
};
__global__ __launch_bounds__(256) void k_sstep(SArgs ea, SArgs ia, const float* __restrict__ fluxg){
  SArgs A = (blockIdx.x==0)? ea : ia;
  const float* G = A.XD; const float* H = A.XD+4096; const float* XG = A.XD+8192;
  const float* Ep = A.ED; const float* Em = A.ED+4096;
  const float* vpm = A.VD+8192; const float* vmm = A.VD+12288; const float* VMv = A.VD+16448;
  __shared__ float Sl[64*65];
  __shared__ float Tt[64*65];
  __shared__ float ACC[64*65];
  __shared__ float xng[64];
  int tid = threadIdx.x;
  for (int i=tid;i<4096;i+=256) Sl[(i>>6)*65+(i&63)] = A.S[i];
  __syncthreads();
  for (int i=tid;i<4096;i+=256){
    int a=i>>6,b=i&63; float s=0.f;
    for (int c=0;c<64;c++) s += (G[a*64+c]-H[a*64+c])*Sl[c*65+b];
    Tt[a*65+b]=s;
  }
  __syncthreads();
  for (int i=tid;i<4096;i+=256){
    int a=i>>6,b=i&63; float s=0.f;
    for (int c=0;c<64;c++) s += Tt[a*65+c]*vpm[c*64+b];
    ACC[a*65+b]=s;
  }
  __syncthreads();
  for (int i=tid;i<4096;i+=256){
    int a=i>>6,b=i&63; float s=0.f;
    for (int c=0;c<64;c++) s += (H[c*64+a]-G[a*64+c])*Sl[c*65+b];
    Tt[a*65+b]=s;
  }
  __syncthreads();
  for (int i=tid;i<4096;i+=256){
    int a=i>>6,b=i&63; float s=0.f;
    for (int c=0;c<64;c++) s += Tt[a*65+c]*vmm[c*64+b];
    ACC[a*65+b]+=s;
  }
  __syncthreads();
  for (int i=tid;i<4096;i+=256){
    int a=i>>6,b=i&63; float s=0.f;
    for (int c=0;c<64;c++) s += Ep[a*64+c]*Sl[c*65+b];
    Tt[a*65+b]=s;
  }
  __syncthreads();
  for (int i=tid;i<4096;i+=256){
    int a=i>>6,b=i&63; float s=0.f;
    for (int c=0;c<64;c++) s += Tt[a*65+c]*A.Vl[b*64+c];
    ACC[a*65+b]+=s;
  }
  __syncthreads();
  for (int i=tid;i<4096;i+=256){
    int a=i>>6,b=i&63; float s=0.f;
    for (int c=0;c<64;c++) s += Em[a*64+c]*Sl[c*65+b];
    Tt[a*65+b]=s;
  }
  __syncthreads();
  for (int i=tid;i<4096;i+=256){
    int a=i>>6,b=i&63; float s=0.f;
    for (int c=0;c<64;c++) s += Tt[a*65+c]*A.Vr[b*64+c];
    ACC[a*65+b]+=s;
  }
  if (tid<64){
    float y=0.f;
    for (int q=0;q<64;q++) y += G[tid*64+q]*A.avec[q];
    xng[tid] = A.nu*DXf*DVf*y + fluxg[1]*XG[tid];
  }
  __syncthreads();
  for (int i=tid;i<4096;i+=256){
    int a=i>>6,b=i&63; float s=0.f;
    for (int c=0;c<64;c++) s += G[a*64+c]*Sl[c*65+b];
    float accv = ACC[a*65+b] + A.nu*DXf*s - xng[a]*VMv[b];
    A.S2[i] = A.S[i] + DTf*accv;
  }
}

// ---------------- Gram (fused, fp64 partials) ----------------
__global__ __launch_bounds__(256) void k_gramf(const float* __restrict__ A0, const float* __restrict__ A1,
                                               int n, double* __restrict__ part){
  __shared__ float At[64][65];
  int sp = blockIdx.y;
  const float* A = sp ? A1 : A0;
  int blk = blockIdx.x, nb = gridDim.x;
  int chunk = n/nb;
  int c0b = blk*chunk;
  int tid=threadIdx.x, ta=tid>>4, tb=tid&15, a0=ta*4, b0=tb*4;
  double acc[4][4];
  #pragma unroll
  for (int ka=0;ka<4;ka++){
    #pragma unroll
    for (int kb=0;kb<4;kb++) acc[ka][kb]=0.0;
  }
  for (int t0=0;t0<chunk;t0+=64){
    int c0=c0b+t0;
    for (int i=tid;i<64*64;i+=256){ int r=i>>6, cc=i&63; At[r][cc]=A[(size_t)r*n + c0+cc]; }
    __syncthreads();
    for (int cc=0;cc<64;cc++){
      float av[4],bv[4];
      #pragma unroll
      for(int k=0;k<4;k++){ av[k]=At[a0+k][cc]; bv[k]=At[b0+k][cc]; }
      #pragma unroll
      for(int ka=0;ka<4;ka++){
        #pragma unroll
        for(int kb=0;kb<4;kb++) acc[ka][kb] += (double)av[ka]*(double)bv[kb];
      }
    }
    __syncthreads();
  }
  double* pb = part + (size_t)(sp*nb+blk)*4096;
  #pragma unroll
  for(int ka=0;ka<4;ka++){
    #pragma unroll
    for(int kb=0;kb<4;kb++) pb[(a0+ka)*64 + b0+kb] = acc[ka][kb];
  }
}

// ---------------- blocked fp32 Cholesky (upper, 64x64, stride-65), NB=8, BD=512 ----------------
__device__ void chol_blk32(float* __restrict__ M, int tid){
  for (int p=0;p<8;p++){
    const int b=8*p;
    if (tid<64){
      float st[8];
      #pragma unroll
      for (int j=0;j<8;j++) st[j] = M[(b+j)*65 + tid];
      #pragma unroll
      for (int kk=0;kk<8;kk++){
        float q[8];
        #pragma unroll
        for (int j=0;j<8;j++) q[j] = __shfl(st[kk], b+j, 64);
        float d = q[kk];
        float rinv = (d > 0.f) ? 1.f/d : 0.f;
        float sk = st[kk];
        #pragma unroll
        for (int j=0;j<8;j++) if (j>kk) st[j] -= q[j]*sk*rinv;
        st[kk] = sk * ((d > 0.f)? rsqrtf(d) : 0.f);
      }
      #pragma unroll
      for (int j=0;j<8;j++) M[(b+j)*65 + tid] = st[j];
    }
    __syncthreads();
    if (b+8 < 64){
      for (int i=(b+8)*64 + tid; i<4096; i+=512){
        int r=i>>6, c=i&63;
        if (c>=r){
          float s=0.f;
          #pragma unroll
          for (int j=0;j<8;j++) s += M[(b+j)*65+r]*M[(b+j)*65+c];
          M[r*65+c] -= s;
        }
      }
    }
    __syncthreads();
  }
}

// ---------------- fused QR v3: fp32, 512 threads ----------------
struct QArgs {
  const double* Gd; const float* A; int n;
  float scaleS, invQ;
  float* SolveM; float* Sout; int outPitch; int mode;
};
__global__ __launch_bounds__(512) void k_qr(QArgs q0, QArgs q1){
  QArgs Q = (blockIdx.x==0)? q0 : q1;
  __shared__ float Lg[64*65];    // G -> R (fp32)
  __shared__ float Lw[64*65];    // R^{-1} (upper)
  __shared__ float Atf[64*65];   // top 64x64 of A
  __shared__ float Cf[64*65];    // bottom-chol C
  __shared__ float Vp[8*129];    // panel reflectors (128 rows)
  __shared__ float TmpI[448];
  __shared__ float Dd[64], Tm[64], vvs[8], tauv[8], Dv[64];
  int tid = threadIdx.x;
  for (int i=tid;i<4096;i+=512) Lg[(i>>6)*65 + (i&63)] = (float)Q.Gd[i];
  for (int i=tid;i<4096;i+=512){ int c=i>>6,x=i&63; Atf[c*65+x] = Q.A[(size_t)c*Q.n + x]; }
  __syncthreads();
  // ---- fp32 blocked Cholesky of G: Lg upper = R ----
  chol_blk32(Lg, tid);
  // ---- Gbot = G - Atop^T Atop (fp64 accum) -> Cf ----
  for (int i=tid;i<4096;i+=512){
    int r=i>>6, c=i&63;
    double s = Q.Gd[i];
    for (int x=0;x<64;x++) s -= (double)Atf[r*65+x]*(double)Atf[c*65+x];
    Cf[r*65+c] = (float)s;
  }
  __syncthreads();
  // ---- fp32 blocked Cholesky of Gbot: Cf upper = C ----
  chol_blk32(Cf, tid);
  // ---- blocked triangular inverse: Lw = R^{-1} ----
  if (tid<64){
    int p=tid>>3, cc=tid&7, b=8*p;
    float wcol[8];
    #pragma unroll
    for (int r=7;r>=0;r--){
      float s = (r==cc)? 1.f : 0.f;
      #pragma unroll
      for (int j=0;j<8;j++) if (j>r) s -= Lg[(b+r)*65 + (b+j)]*wcol[j];
      float dg = Lg[(b+r)*65 + (b+r)];
      wcol[r] = (r<=cc && dg!=0.f)? s/dg : 0.f;
    }
    #pragma unroll
    for (int r=0;r<8;r++) Lw[(b+r)*65 + (b+cc)] = wcol[r];
  }
  __syncthreads();
  for (int d=1; d<8; d++){
    int nb2 = 8-d;
    if (tid < nb2*64){
      int bb=tid>>6, rc=tid&63, r=rc>>3, c=rc&7;
      int p=bb, qb=p+d;
      float s=0.f;
      for (int m=p+1;m<=qb;m++){
        #pragma unroll
        for (int jj=0;jj<8;jj++)
          s += Lg[(8*p+r)*65 + 8*m+jj]*Lw[(8*m+jj)*65 + 8*qb+c];
      }
      TmpI[tid]=s;
    }
    __syncthreads();
    if (tid < nb2*64){
      int bb=tid>>6, rc=tid&63, r=rc>>3, c=rc&7;
      int p=bb, qb=p+d;
      float s=0.f;
      #pragma unroll
      for (int rr=0;rr<8;rr++)
        s += Lw[(8*p+r)*65 + 8*p+rr]*TmpI[(bb<<6)+(rr<<3)+c];
      Lw[(8*p+r)*65 + 8*qb+c] = -s;
    }
    __syncthreads();
  }
  // ---- blocked Householder on [Atop ; C] (128x64), compact-WY, 8 lanes/col ----
  int col = tid>>3, l8 = tid&7;
  float a[16];
  #pragma unroll
  for (int j=0;j<16;j++){
    int row = l8 + 8*j;
    if (row < 64) a[j] = Atf[col*65 + row];
    else { int r = row - 64; a[j] = (col>=r)? Cf[r*65+col] : 0.f; }
  }
  for (int p8=0;p8<8;p8++){
    const int b = 8*p8;
    // Phase A: panel = wave p8 (cols b..b+7)
    if (col>=b && col<b+8){
      #pragma unroll 1
      for (int kk=0;kk<8;kk++){
        int k = b+kk;
        float sg=0.f, al=0.f;
        #pragma unroll
        for (int j=0;j<16;j++){
          int row = l8 + 8*j;
          float v = (row>=k)? a[j] : 0.f;
          sg += v*v;
          al += (row==k)? a[j] : 0.f;
        }
        sg += __shfl_xor(sg,1,64); sg += __shfl_xor(sg,2,64); sg += __shfl_xor(sg,4,64);
        al += __shfl_xor(al,1,64); al += __shfl_xor(al,2,64); al += __shfl_xor(al,4,64);
        float sgb = __shfl(sg, kk*8, 64);
        float alb = __shfl(al, kk*8, 64);
        float beta = (alb >= 0.f)? -sqrtf(sgb) : sqrtf(sgb);
        float vk = alb - beta;
        float vv = sgb - alb*beta;
        if (col==k){
          #pragma unroll
          for (int j=0;j<16;j++){
            int row = l8 + 8*j;
            a[j] = (row<k)? 0.f : ((row==k)? vk : a[j]);
          }
          #pragma unroll
          for (int j=0;j<16;j++) Vp[kk*129 + l8 + 8*j] = a[j];
          if (l8==0){ Dv[k] = (beta >= 0.f)? 1.f : -1.f; vvs[kk] = vv; }
        }
        float vj[16]; float s=0.f;
        #pragma unroll
        for (int j=0;j<16;j++){ vj[j] = __shfl(a[j], kk*8 + l8, 64); s += vj[j]*a[j]; }
        s += __shfl_xor(s,1,64); s += __shfl_xor(s,2,64); s += __shfl_xor(s,4,64);
        if (col>k && vv > 0.f){
          float f = s/vv;
          #pragma unroll
          for (int j=0;j<16;j++) a[j] -= f*vj[j];
        }
      }
    }
    __syncthreads();
    // B1: pairwise reflector dots + tau
    {
      int pr = tid>>3, m = pr>>3, i2 = pr&7;
      float sd=0.f;
      #pragma unroll
      for (int j=0;j<16;j++){ int row = l8 + 8*j; sd += Vp[m*129+row]*Vp[i2*129+row]; }
      sd += __shfl_xor(sd,1,64); sd += __shfl_xor(sd,2,64); sd += __shfl_xor(sd,4,64);
      if (l8==0 && m<i2) Dd[m*8+i2]=sd;
      if (tid<8) tauv[tid] = (vvs[tid]>0.f)? 1.f/vvs[tid] : 0.f;
    }
    __syncthreads();
    // B2: build T
    if (tid<8){
      int j=tid;
      for (int i2=0;i2<8;i2++){
        if (i2==j) Tm[j*8+j]=tauv[j];
        else if (i2>j){
          float s2=0.f;
          for (int m=j;m<i2;m++) s2 += Tm[j*8+m]*Dd[m*8+i2];
          Tm[j*8+i2] = -tauv[i2]*s2;
        } else Tm[j*8+i2]=0.f;
      }
    }
    __syncthreads();
    // B3: block-apply: a -= V (T^T (V^T a))
    if (col >= b+8){
      float z[8];
      #pragma unroll
      for (int kk=0;kk<8;kk++){
        float s2=0.f;
        #pragma unroll
        for (int j=0;j<16;j++){ int row = l8 + 8*j; s2 += Vp[kk*129+row]*a[j]; }
        s2 += __shfl_xor(s2,1,64); s2 += __shfl_xor(s2,2,64); s2 += __shfl_xor(s2,4,64);
        z[kk]=s2;
      }
      float y[8];
      #pragma unroll
      for (int kk=0;kk<8;kk++){
        float s2=0.f;
        #pragma unroll
        for (int m=0;m<8;m++) if (m<=kk) s2 += Tm[m*8+kk]*z[m];
        y[kk]=s2;
      }
      #pragma unroll
      for (int j=0;j<16;j++){
        int row = l8 + 8*j;
        float s2=0.f;
        #pragma unroll
        for (int kk=0;kk<8;kk++) s2 += Vp[kk*129+row]*y[kk];
        a[j] -= s2;
      }
    }
    __syncthreads();
  }
  // ---- outputs ----
  for (int i=tid;i<4096;i+=512){
    int r=i>>6, q2=i&63;
    Q.SolveM[i] = (q2<=r)? (Dv[r]*Lw[q2*65+r]*Q.invQ) : 0.f;
    if (Q.mode==0){
      Q.Sout[i] = (q2>=r)? (Dv[r]*Lg[r*65+q2]*Q.scaleS) : 0.f;
    } else {
      Q.Sout[(size_t)r*Q.outPitch + q2] = (r>=q2)? (Dv[q2]*Lg[q2*65+r]*Q.scaleS) : 0.f;
    }
  }
}

// ---------------- Q formation (fused species) ----------------
__global__ __launch_bounds__(256) void k_qformf(const float* __restrict__ A0, const float* __restrict__ A1,
    int n, const float* __restrict__ M0, const float* __restrict__ M1,
    float* __restrict__ O0, float* __restrict__ O1, int pitch)
{
  int sp = blockIdx.y >> 2;
  const float* A = sp ? A1 : A0;
  const float* M = sp ? M1 : M0;
  float* Out = sp ? O1 : O0;
  int x = blockIdx.x*256 + threadIdx.x;
  int r0 = (blockIdx.y & 3)*16;
  float acc[16];
  #pragma unroll
  for (int rr=0;rr<16;rr++) acc[rr]=0.f;
  for (int q=0;q<64;q++){
    float aq = A[(size_t)q*n + x];
    #pragma unroll
    for (int rr=0;rr<16;rr++) acc[rr] += M[(r0+rr)*64 + q]*aq;
  }
  #pragma unroll
  for (int rr=0;rr<16;rr++) Out[(size_t)(r0+rr)*pitch + x] = acc[rr];
}

// ======================= host =======================
extern "C" void kernel_launch(void* const* d_in, const int* in_sizes, int n_in,
                              void* d_out, int out_size, void* d_ws, size_t ws_size,
                              hipStream_t stream)
{
  (void)in_sizes; (void)n_in; (void)out_size; (void)ws_size;
  const float* Xe = (const float*)d_in[0];
  const float* Se = (const float*)d_in[1];
  const float* Ve = (const float*)d_in[2];
  const float* Xi = (const float*)d_in[3];
  const float* Si = (const float*)d_in[4];
  const float* Vi = (const float*)d_in[5];
  float* out = (float*)d_out;
  float* w = (float*)d_ws;

  size_t o = 0;
  auto alloc = [&](size_t nn){ size_t r=o; o += (nn+63)&~(size_t)63; return r; };
  size_t F_VD = alloc(2*PS_V);
  size_t F_XD = alloc(2*PS_X);
  size_t F_ED = alloc(2*PS_E);
  size_t F_VL_E = alloc(4096), F_VR_E = alloc(4096), F_VL_I = alloc(4096), F_VR_I = alloc(4096);
  size_t F_SC_E = alloc(4096), F_SC_I = alloc(4096), F_S2_E = alloc(4096), F_S2_I = alloc(4096);
  size_t F_SOLVE_E = alloc(4096), F_SOLVE_I = alloc(4096);
  size_t F_AE = alloc(64), F_AI = alloc(64), F_XNGE = alloc(64), F_XNGI = alloc(64);
  size_t F_FLUX = alloc(64);
  size_t F_GSH = alloc(NXC);
  size_t F_RHO = alloc(NXC);
  size_t F_E   = alloc(NXC);
  size_t F_KE = alloc((size_t)64*NXC);
  size_t F_KI = alloc((size_t)64*NXC);
  size_t F_LE = F_KE;
  size_t F_LI = F_KI;
  size_t F_PART = alloc(1060864);
  size_t F_GQR = alloc(16384);   // 8192 doubles (2 species)
  double* Gqr = (double*)(w + F_GQR);
  double* partd = (double*)(w + F_PART);
  float* part = w + F_PART;
  const float* VDe = w + F_VD;
  const float* VDi = w + F_VD + PS_V;
  const float* XDe = w + F_XD;
  const float* XDi = w + F_XD + PS_X;
  const float* EDe = w + F_ED;
  const float* EDi = w + F_ED + PS_E;

  float sqDX = sqrtf(DXf), isqDX = 1.f/sqrtf(DXf);
  float sqDV = sqrtf(DVf), isqDV = 1.f/sqrtf(DVf);
  const float NUE = 1.0f, NUI = 0.04f;
  const float FACE = -1.0f, FACI = 1.0f/1836.0f;

  // --- V-derived stats ---
  k_vstatsf<<<dim3(32,2),256,0,stream>>>(Ve, Vi, part);
  k_reduce32f<<<dim3((PS_V+255)/256,2),256,0,stream>>>(part, 32, PS_V, w+F_VD);
  k_gshape<<<1,1024,0,stream>>>(w+F_GSH);
  k_prep1<<<1,256,0,stream>>>(Ve, Vi, Se, Si, Xi, VDe, VDi,
                              w+F_VL_E, w+F_VR_E, w+F_VL_I, w+F_VR_I,
                              w+F_AE, w+F_AI, w+F_FLUX);
  // --- K step ---
  k_rho<<<NXC/256,256,0,stream>>>(Xe, NXC, Xi, NXC, w+F_AE, w+F_AI, w+F_RHO);
  k_poisson<<<1,1024,0,stream>>>(w+F_RHO, w+F_E);
  KArg ke{Xe, Se, VDe, w+F_VL_E, w+F_VR_E, NUE, FACE, w+F_KE};
  KArg ki{Xi, Si, VDi, w+F_VL_I, w+F_VR_I, NUI, FACI, w+F_KI};
  k_kstepf<<<dim3(NXC/64,2),256,0,stream>>>(ke, ki, w+F_E, w+F_GSH, w+F_FLUX);
  // --- QR of K^T (both species) ---
  k_gramf<<<dim3(64,2),256,0,stream>>>(w+F_KE, w+F_KI, NXC, partd);
  k_reduce64f<<<dim3(16,2),256,0,stream>>>(partd, 64, Gqr);
  {
    QArgs qe{Gqr,        w+F_KE, NXC, sqDX, isqDX, w+F_SOLVE_E, w+F_SC_E, 0, 0};
    QArgs qi{Gqr+4096,   w+F_KI, NXC, sqDX, isqDX, w+F_SOLVE_I, w+F_SC_I, 0, 0};
    k_qr<<<2,512,0,stream>>>(qe, qi);
  }
  k_qformf<<<dim3(NXC/256,8),256,0,stream>>>(w+F_KE, w+F_KI, NXC, w+F_SOLVE_E, w+F_SOLVE_I,
                                             out, out + (size_t)64*OUTWC, OUTWC);
  // --- X stats on new X ---
  k_xstatsf<<<dim3(64,2),256,0,stream>>>(out, out + (size_t)64*OUTWC, OUTWC, w+F_GSH, part);
  k_reduce32f<<<dim3((PS_X+255)/256,2),256,0,stream>>>(part, 64, PS_X, w+F_XD);
  // --- S step ---
  k_prep2<<<1,256,0,stream>>>(w+F_SC_E, w+F_SC_I, VDe, VDi, out + (size_t)64*OUTWC,
                              w+F_AE, w+F_AI, w+F_FLUX);
  k_rho<<<NXC/256,256,0,stream>>>(out, OUTWC, out + (size_t)64*OUTWC, OUTWC, w+F_AE, w+F_AI, w+F_RHO);
  k_poisson<<<1,1024,0,stream>>>(w+F_RHO, w+F_E);
  k_eweightf<<<dim3(64,2),256,0,stream>>>(out, out + (size_t)64*OUTWC, OUTWC, w+F_E, FACE, FACI, part);
  k_reduce32f<<<dim3((PS_E+255)/256,2),256,0,stream>>>(part, 64, PS_E, w+F_ED);
  SArgs ea; ea.S=w+F_SC_E; ea.XD=XDe; ea.ED=EDe; ea.VD=VDe; ea.Vl=w+F_VL_E; ea.Vr=w+F_VR_E; ea.avec=w+F_AE; ea.S2=w+F_S2_E; ea.nu=NUE;
  SArgs ia; ia.S=w+F_SC_I; ia.XD=XDi; ia.ED=EDi; ia.VD=VDi; ia.Vl=w+F_VL_I; ia.Vr=w+F_VR_I; ia.avec=w+F_AI; ia.S2=w+F_S2_I; ia.nu=NUI;
  k_sstep<<<2,256,0,stream>>>(ea, ia, w+F_FLUX);
  // --- L step ---
  k_prep3<<<1,256,0,stream>>>(w+F_S2_E, w+F_S2_I, VDe, VDi, out + (size_t)64*OUTWC,
                              XDe, XDi, w+F_AE, w+F_AI, w+F_XNGE, w+F_XNGI, w+F_FLUX);
  k_rho<<<NXC/256,256,0,stream>>>(out, OUTWC, out + (size_t)64*OUTWC, OUTWC, w+F_AE, w+F_AI, w+F_RHO);
  k_poisson<<<1,1024,0,stream>>>(w+F_RHO, w+F_E);
  k_eweightf<<<dim3(64,2),256,0,stream>>>(out, out + (size_t)64*OUTWC, OUTWC, w+F_E, FACE, FACI, part);
  k_reduce32f<<<dim3((PS_E+255)/256,2),256,0,stream>>>(part, 64, PS_E, w+F_ED);
  LArg le{Ve, w+F_S2_E, EDe, XDe, w+F_XNGE, NUE, 1.0f,    w+F_LE};
  LArg li{Vi, w+F_S2_I, EDi, XDi, w+F_XNGI, NUI, 1836.0f, w+F_LI};
  k_lstepf<<<dim3(NVC/64,2),256,0,stream>>>(le, li);
  // --- QR of L^T (both species) ---
  k_gramf<<<dim3(32,2),256,0,stream>>>(w+F_LE, w+F_LI, NVC, partd);
  k_reduce64f<<<dim3(16,2),256,0,stream>>>(partd, 32, Gqr);
  {
    QArgs qe{Gqr,      w+F_LE, NVC, sqDV, isqDV, w+F_SOLVE_E, out + NXC,                        OUTWC, 1};
    QArgs qi{Gqr+4096, w+F_LI, NVC, sqDV, isqDV, w+F_SOLVE_I, out + (size_t)64*OUTWC + NXC,     OUTWC, 1};
    k_qr<<<2,512,0,stream>>>(qe, qi);
  }
  k_qformf<<<dim3(NVC/256,8),256,0,stream>>>(w+F_LE, w+F_LI, NVC, w+F_SOLVE_E, w+F_SOLVE_I,
                                             out + NXC + 64, out + (size_t)64*OUTWC + NXC + 64, OUTWC);
}

// Round 7
// 1307.736 us; speedup vs baseline: 1.4064x; 1.1326x over previous
//
#include <hip/hip_runtime.h>
#include <math.h>

#define NXC 32768
#define NVC 16384
#define OUTWC (NXC + 64 + NVC)

static constexpr float DXf   = 1.0f/32768.0f;
static constexpr float DVf   = 16.0f/16384.0f;
static constexpr float DTf   = 1e-3f;
static constexpr float VMAXf = 8.0f;
static constexpr float INV2PI= 0.15915494309189535f;

#define PS_V 16576
#define PS_X 8256
#define PS_E 8192

// ---------------- gshape ----------------
__global__ __launch_bounds__(1024) void k_gshape(float* __restrict__ g){
  __shared__ float red[1024];
  int t = threadIdx.x;
  float s = 0.f;
  for (int i = t; i < NXC; i += 1024){
    float x = (i + 0.5f)*DXf - 0.5f;
    float xx = x*10.0f;
    float gv = expf(-0.5f*xx*xx);
    g[i] = gv; s += gv;
  }
  red[t] = s; __syncthreads();
  for (int o = 512; o > 0; o >>= 1){ if (t < o) red[t] += red[t+o]; __syncthreads(); }
  float norm = 1.0f/(red[0]*DXf);
  for (int i = t; i < NXC; i += 1024) g[i] *= norm;
}

// ---------------- V stats (fused species via grid.y, blocks via grid.x) ----------------
__global__ __launch_bounds__(256) void k_vstatsf(const float* __restrict__ V0, const float* __restrict__ V1,
                                                 float* __restrict__ part){
  __shared__ float Vt[64][66];
  int sp = blockIdx.y;
  const float* V = sp ? V1 : V0;
  float Amax = sp ? 1836.0f : 1.0f;
  int blk = blockIdx.x;
  int nbk = gridDim.x;
  int chunk = NVC/nbk;
  int c0b = blk*chunk;
  int tid = threadIdx.x;
  int ta = tid >> 4, tb = tid & 15;
  int a0 = ta*4, b0 = tb*4;
  float acc0[4][4]={{0}}, acc1[4][4]={{0}}, accp[4][4]={{0}}, accm[4][4]={{0}};
  float vsv[4]={0,0,0,0}, vvm[4]={0,0,0,0}, vwv[4]={0,0,0,0};
  float fm = sqrtf(Amax*INV2PI);
  for (int t0 = 0; t0 < chunk; t0 += 64){
    int c0 = c0b + t0;
    for (int i = tid; i < 64*65; i += 256){
      int r = i/65, cc = i%65;
      int c = c0 - 1 + cc;
      Vt[r][cc] = (c >= 0 && c < NVC) ? V[(size_t)r*NVC + c] : 0.f;
    }
    __syncthreads();
    for (int jj = 0; jj < 64; ++jj){
      int j = c0 + jj;
      float vs = -VMAXf + (j + 0.5f)*DVf;
      float wpj = (vs > 0.f ? vs : 0.f)*DVf;
      float wmj = (vs < 0.f ? vs : 0.f)*DVf;
      float av[4], bv[4], bm[4];
      #pragma unroll
      for (int k=0;k<4;k++){ av[k]=Vt[a0+k][jj+1]; bv[k]=Vt[b0+k][jj+1]; bm[k]=Vt[b0+k][jj]; }
      float lag = (j >= 1) ? 1.f : 0.f;
      #pragma unroll
      for (int ka=0;ka<4;ka++){
        #pragma unroll
        for (int kb=0;kb<4;kb++){
          float p = av[ka]*bv[kb];
          acc0[ka][kb] += p;
          accp[ka][kb] += p*wpj;
          accm[ka][kb] += p*wmj;
          acc1[ka][kb] += lag*av[ka]*bm[kb];
        }
      }
      if (tb == 0){
        float mv = fm*expf(-0.5f*Amax*vs*vs)*DVf;
        #pragma unroll
        for (int k=0;k<4;k++){
          vsv[k] += av[k];
          vvm[k] += av[k]*mv;
          vwv[k] += av[k]*wpj;
        }
      }
    }
    __syncthreads();
  }
  float* pb = part + (size_t)(sp*nbk+blk)*PS_V;
  #pragma unroll
  for (int ka=0;ka<4;ka++){
    #pragma unroll
    for (int kb=0;kb<4;kb++){
      int idx = (a0+ka)*64 + (b0+kb);
      pb[idx]        = acc0[ka][kb];
      pb[4096+idx]   = acc1[ka][kb];
      pb[8192+idx]   = accp[ka][kb];
      pb[12288+idx]  = accm[ka][kb];
    }
  }
  if (tb == 0){
    #pragma unroll
    for (int k=0;k<4;k++){
      pb[16384 + a0+k] = vsv[k];
      pb[16448 + a0+k] = vvm[k];
      pb[16512 + a0+k] = vwv[k];
    }
  }
}

// ---------------- X stats (fused) ----------------
__global__ __launch_bounds__(256) void k_xstatsf(const float* __restrict__ X0, const float* __restrict__ X1,
                                                 int pitch, const float* __restrict__ gsh, float* __restrict__ part){
  __shared__ float Xt[64][66];
  int sp = blockIdx.y;
  const float* X = sp ? X1 : X0;
  int blk = blockIdx.x;               // 64 per species
  int chunk = NXC/64;                 // 512
  int c0b = blk*chunk;
  int tid = threadIdx.x, ta = tid>>4, tb = tid&15, a0 = ta*4, b0 = tb*4;
  float accg[4][4]={{0}}, acch[4][4]={{0}};
  float axg[4]={0,0,0,0};
  for (int t0=0;t0<chunk;t0+=64){
    int c0 = c0b+t0;
    for (int i=tid;i<64*65;i+=256){
      int r=i/65, cc=i%65; int x=c0-1+cc;
      Xt[r][cc] = (x>=0 && x<NXC) ? X[(size_t)r*pitch + x] : 0.f;
    }
    __syncthreads();
    for (int jj=0;jj<64;jj++){
      int x = c0+jj;
      float av[4],bv[4],bm[4];
      #pragma unroll
      for (int k=0;k<4;k++){ av[k]=Xt[a0+k][jj+1]; bv[k]=Xt[b0+k][jj+1]; bm[k]=Xt[b0+k][jj]; }
      float lag = (x>=1)?1.f:0.f;
      #pragma unroll
      for (int ka=0;ka<4;ka++){
        #pragma unroll
        for (int kb=0;kb<4;kb++){
          accg[ka][kb] += av[ka]*bv[kb];
          acch[ka][kb] += lag*av[ka]*bm[kb];
        }
      }
      if (tb==0){
        float gw = gsh[x]*DXf;
        #pragma unroll
        for (int k=0;k<4;k++) axg[k] += av[k]*gw;
      }
    }
    __syncthreads();
  }
  float* pb = part + (size_t)(sp*64+blk)*PS_X;
  #pragma unroll
  for (int ka=0;ka<4;ka++){
    #pragma unroll
    for (int kb=0;kb<4;kb++){
      int idx = (a0+ka)*64 + (b0+kb);
      pb[idx] = accg[ka][kb];
      pb[4096+idx] = acch[ka][kb];
    }
  }
  if (tb==0){
    #pragma unroll
    for (int k=0;k<4;k++) pb[8192 + a0+k] = axg[k];
  }
}

// ---------------- E-weighted grams (fused) ----------------
__global__ __launch_bounds__(256) void k_eweightf(const float* __restrict__ X0, const float* __restrict__ X1,
                                                  int pitch, const float* __restrict__ E,
                                                  float fac0, float fac1, float* __restrict__ part){
  __shared__ float Xt[64][65];
  __shared__ float Ew[64];
  int sp = blockIdx.y;
  const float* X = sp ? X1 : X0;
  float fac = sp ? fac1 : fac0;
  int blk = blockIdx.x; int chunk = NXC/64; int c0b = blk*chunk;
  int tid = threadIdx.x, ta = tid>>4, tb = tid&15, a0 = ta*4, b0 = tb*4;
  float accp[4][4]={{0}}, accm[4][4]={{0}};
  for (int t0=0;t0<chunk;t0+=64){
    int c0 = c0b+t0;
    for (int i=tid;i<64*64;i+=256){
      int r=i>>6, cc=i&63;
      Xt[r][cc] = X[(size_t)r*pitch + c0+cc];
    }
    if (tid < 64) Ew[tid] = E[c0+tid]*fac;
    __syncthreads();
    for (int jj=0;jj<64;jj++){
      float w0 = Ew[jj];
      float wp = (w0>0.f?w0:0.f)*DXf, wm = (w0<0.f?w0:0.f)*DXf;
      float av[4],bv[4];
      #pragma unroll
      for (int k=0;k<4;k++){ av[k]=Xt[a0+k][jj]; bv[k]=Xt[b0+k][jj]; }
      #pragma unroll
      for (int ka=0;ka<4;ka++){
        #pragma unroll
        for (int kb=0;kb<4;kb++){
          float p = av[ka]*bv[kb];
          accp[ka][kb] += p*wp;
          accm[ka][kb] += p*wm;
        }
      }
    }
    __syncthreads();
  }
  float* pb = part + (size_t)(sp*64+blk)*PS_E;
  #pragma unroll
  for (int ka=0;ka<4;ka++){
    #pragma unroll
    for (int kb=0;kb<4;kb++){
      int idx = (a0+ka)*64 + (b0+kb);
      pb[idx] = accp[ka][kb];
      pb[4096+idx] = accm[ka][kb];
    }
  }
}

// ---------------- reductions (fused species via grid.y) ----------------
__global__ __launch_bounds__(256) void k_reduce32f(const float* __restrict__ part, int nb, int ps,
                                                   float* __restrict__ dst){
  int sp = blockIdx.y;
  int i = blockIdx.x*256 + threadIdx.x;
  if (i < ps){
    float s = 0.f;
    for (int b=0;b<nb;b++) s += part[(size_t)(sp*nb+b)*ps + i];
    dst[(size_t)sp*ps + i] = s;
  }
}
__global__ __launch_bounds__(256) void k_reduce64f(const double* __restrict__ part, int nb,
                                                   double* __restrict__ dst){
  int sp = blockIdx.y;
  int i = blockIdx.x*256 + threadIdx.x;
  if (i < 4096){
    double s = 0.0;
    for (int b=0;b<nb;b++) s += part[(size_t)(sp*nb+b)*4096 + i];
    dst[(size_t)sp*4096 + i] = s;
  }
}

// ---------------- prep kernels ----------------
__global__ __launch_bounds__(256) void k_prep1(
  const float* __restrict__ Ve, const float* __restrict__ Vi,
  const float* __restrict__ Se, const float* __restrict__ Si, const float* __restrict__ Xi,
  const float* __restrict__ VDe, const float* __restrict__ VDi,
  float* __restrict__ Vle, float* __restrict__ Vre, float* __restrict__ Vli, float* __restrict__ Vri,
  float* __restrict__ ae, float* __restrict__ ai, float* __restrict__ fluxg)
{
  int t = threadIdx.x;
  const float* g0e = VDe; const float* g1e = VDe+4096;
  const float* g0i = VDi; const float* g1i = VDi+4096;
  const float* sVe = VDe+16384; const float* sVi = VDi+16384;
  const float* wvi = VDi+16512;
  for (int i=t;i<4096;i+=256){
    int a=i>>6, b=i&63;
    float v0a=Ve[(size_t)a*NVC], v0b=Ve[(size_t)b*NVC];
    float vea=Ve[(size_t)a*NVC+NVC-1], veb=Ve[(size_t)b*NVC+NVC-1];
    Vle[i] = (g0e[i] - v0a*v0b) - g1e[i];
    Vre[i] = g1e[b*64+a] - g0e[i] + vea*veb;
    float w0a=Vi[(size_t)a*NVC], w0b=Vi[(size_t)b*NVC];
    float wea=Vi[(size_t)a*NVC+NVC-1], web=Vi[(size_t)b*NVC+NVC-1];
    Vli[i] = (g0i[i] - w0a*w0b) - g1i[i];
    Vri[i] = g1i[b*64+a] - g0i[i] + wea*web;
  }
  __shared__ float red[64];
  if (t < 64){
    float s1=0.f,s2=0.f,tr=0.f;
    for (int q=0;q<64;q++){
      s1 += Se[t*64+q]*sVe[q];
      s2 += Si[t*64+q]*sVi[q];
      tr += Xi[(size_t)q*NXC + (NXC-1)]*Si[q*64+t];
    }
    ae[t]=s1; ai[t]=s2; red[t]=tr*wvi[t];
  }
  __syncthreads();
  if (t==0){ float s=0.f; for (int r=0;r<64;r++) s+=red[r]; fluxg[0]=s; }
}

__global__ __launch_bounds__(256) void k_prep2(const float* __restrict__ Sce, const float* __restrict__ Sci,
    const float* __restrict__ VDe, const float* __restrict__ VDi, const float* __restrict__ XiN,
    float* __restrict__ ae, float* __restrict__ ai, float* __restrict__ fluxg)
{
  const float* sVe = VDe+16384; const float* sVi = VDi+16384; const float* wvi = VDi+16512;
  __shared__ float red[64];
  int t=threadIdx.x;
  if (t<64){
    float s1=0.f,s2=0.f,tr=0.f;
    for (int q=0;q<64;q++){
      s1 += Sce[t*64+q]*sVe[q];
      s2 += Sci[t*64+q]*sVi[q];
      tr += XiN[(size_t)q*OUTWC + (NXC-1)]*Sci[q*64+t];
    }
    ae[t]=s1; ai[t]=s2; red[t]=tr*wvi[t];
  }
  __syncthreads();
  if (t==0){ float s=0.f; for(int r=0;r<64;r++) s+=red[r]; fluxg[1]=s; }
}

__global__ __launch_bounds__(256) void k_prep3(const float* __restrict__ S2e, const float* __restrict__ S2i,
    const float* __restrict__ VDe, const float* __restrict__ VDi, const float* __restrict__ XiN,
    const float* __restrict__ XDe, const float* __restrict__ XDi,
    float* __restrict__ ae, float* __restrict__ ai,
    float* __restrict__ Xnge, float* __restrict__ Xngi, float* __restrict__ fluxg)
{
  const float* sVe = VDe+16384; const float* sVi = VDi+16384; const float* wvi = VDi+16512;
  const float* Ge = XDe; const float* Gi = XDi;
  const float* XGe = XDe+8192; const float* XGi = XDi+8192;
  __shared__ float red[64];
  int t=threadIdx.x;
  if (t<64){
    float s1=0.f,s2=0.f,tr=0.f;
    for (int q=0;q<64;q++){
      s1 += S2e[t*64+q]*sVe[q];
      s2 += S2i[t*64+q]*sVi[q];
      tr += XiN[(size_t)q*OUTWC + (NXC-1)]*S2i[q*64+t];
    }
    ae[t]=s1; ai[t]=s2; red[t]=tr*wvi[t];
  }
  __syncthreads();
  if (t==0){ float s=0.f; for(int r=0;r<64;r++) s+=red[r]; fluxg[2]=s; }
  __syncthreads();
  if (t<64){
    float y1=0.f,y2=0.f;
    for (int q=0;q<64;q++){ y1 += Ge[t*64+q]*ae[q]; y2 += Gi[t*64+q]*ai[q]; }
    float f3 = fluxg[2];
    Xnge[t] = 1.0f *DXf*DVf*y1 + f3*XGe[t];
    Xngi[t] = 0.04f*DXf*DVf*y2 + f3*XGi[t];
  }
}

// ---------------- rho ----------------
__global__ __launch_bounds__(256) void k_rho(const float* __restrict__ Xe, int pe,
                                             const float* __restrict__ Xi, int pi,
                                             const float* __restrict__ ae, const float* __restrict__ ai,
                                             float* __restrict__ rho){
  int x = blockIdx.x*256 + threadIdx.x;
  float s = 0.f;
  for (int r=0;r<64;r++) s += ai[r]*Xi[(size_t)r*pi + x] - ae[r]*Xe[(size_t)r*pe + x];
  rho[x] = DVf*s;
}

// ---------------- poisson ----------------
__global__ __launch_bounds__(1024) void k_poisson(const float* __restrict__ rho, float* __restrict__ E){
  __shared__ float wsum[16];
  __shared__ float bsum[16];
  int t = threadIdx.x;
  int base = t*32;
  float loc[32];
  float run = 0.f;
  #pragma unroll
  for (int i=0;i<32;i++){ run += rho[base+i]; loc[i]=run; }
  float v = run;
  for (int off=1; off<64; off<<=1){
    float u = __shfl_up(v, off, 64);
    if ((t&63) >= off) v += u;
  }
  int wave = t>>6;
  if ((t&63)==63) wsum[wave] = v;
  __syncthreads();
  if (t==0){
    float a=0.f;
    for (int w0=0;w0<16;w0++){ float x=wsum[w0]; wsum[w0]=a; a+=x; }
  }
  __syncthreads();
  float offset = wsum[wave] + (v - run);
  float msum = 0.f;
  #pragma unroll
  for (int i=0;i<32;i++){ float e = DXf*(offset + loc[i]); loc[i]=e; msum += e; }
  float rs2 = msum;
  for (int off=32; off>0; off>>=1) rs2 += __shfl_down(rs2, off, 64);
  if ((t&63)==0) bsum[wave]=rs2;
  __syncthreads();
  if (t==0){ float a=0.f; for(int w0=0;w0<16;w0++) a+=bsum[w0]; bsum[0]=a; }
  __syncthreads();
  float mean = bsum[0]/(float)NXC;
  #pragma unroll
  for (int i=0;i<32;i++) E[base+i] = loc[i]-mean;
}

// ---------------- K step v3: 32-col tiles, 2 blocks/CU, broadcast reads ----------------
struct KArg { const float *X, *S, *VD, *Vl, *Vr; float nu, fac; float* Kout; };
__global__ __launch_bounds__(256) void k_kstepf(KArg k0, KArg k1,
    const float* __restrict__ E, const float* __restrict__ gsh, const float* __restrict__ fluxg)
{
  KArg A = blockIdx.y ? k1 : k0;
  __shared__ float Kt[64*34];     // Kt[q*34+cc], cc = local col + 1 halo each side
  __shared__ float Mv[4*4160];    // 4 slots of 64x65
  __shared__ float sVs[64], VMs[64];
  float* Sl = Mv;                 // slot0: S (stride 65)  [phase 0-1]
  float* Xt = Mv + 4160;          // slot1: X tile 64x34   [phase 0-1]
  int x0 = blockIdx.x*32;
  int tid = threadIdx.x;
  // phase 0: stage S, X tile, Vl->slot2, Vr->slot3, vectors
  for (int i=tid;i<4096;i+=256) Sl[(i>>6)*65+(i&63)] = A.S[i];
  for (int i=tid;i<64*34;i+=256){
    int r=i/34, cc=i%34; int x = x0-1+cc;
    Xt[i] = (x>=0 && x<NXC)? A.X[(size_t)r*NXC+x] : 0.f;
  }
  for (int i=tid;i<4096;i+=256){
    int r=i>>6,c=i&63;
    Mv[2*4160 + r*65+c] = A.Vl[i];
    Mv[3*4160 + r*65+c] = A.Vr[i];
  }
  if (tid<64){ sVs[tid]=A.VD[16384+tid]; VMs[tid]=A.VD[16448+tid]; }
  __syncthreads();
  // phase 1: Kt[q][cc] = sum_p S[p][q]*X[p][cc]
  for (int i=tid;i<64*34;i+=256){
    int q=i/34, cc=i%34;
    float a=0.f;
    for (int p=0;p<64;p++) a += Sl[p*65+q]*Xt[p*34+cc];
    Kt[i]=a;
  }
  __syncthreads();
  // phase 2: overwrite slot0/1 with vpm, vmm
  {
    const float* vpm = A.VD + 8192;
    const float* vmm = A.VD + 12288;
    for (int i=tid;i<4096;i+=256){
      int r=i>>6,c=i&63;
      Mv[0*4160 + r*65+c]=vpm[i];
      Mv[1*4160 + r*65+c]=vmm[i];
    }
  }
  __syncthreads();
  // phase 3: main loop. wave owns 8 columns; lane = row r.
  int r = tid & 63, w8 = (tid>>6)*8;
  float fo = fluxg[0];
  const float DTDX = DTf/DXf;
  float acc[8], nacc[8], epv[8], emv[8];
  #pragma unroll
  for (int c=0;c<8;c++){
    int x = x0 + w8 + c;
    float Ex = A.fac*E[x];
    epv[c] = DTf*(Ex>0.f?Ex:0.f); emv[c] = DTf*(Ex<0.f?Ex:0.f);
    acc[c]=0.f; nacc[c]=0.f;
  }
  for (int q=0;q<64;q++){
    float vp_ = DTDX*Mv[0*4160 + r*65+q];
    float vm_ = DTDX*Mv[1*4160 + r*65+q];
    float vl  = Mv[2*4160 + r*65+q];
    float vr  = Mv[3*4160 + r*65+q];
    float sq  = sVs[q];
    float w0 = vm_ - vp_;
    float kseg[10];
    #pragma unroll
    for (int c=0;c<10;c++) kseg[c] = Kt[q*34 + w8 + c];
    #pragma unroll
    for (int c=0;c<8;c++){
      float kk0 = kseg[c+1];
      float t = w0 - (epv[c]*vl + emv[c]*vr);
      acc[c] += t*kk0 + vp_*kseg[c] - vm_*kseg[c+2];
      nacc[c] += sq*kk0;
    }
  }
  float vmr = VMs[r];
  #pragma unroll
  for (int c=0;c<8;c++){
    int x = x0 + w8 + c;
    float y = Kt[r*34 + w8 + c + 1]*(1.f - DTf*A.nu) + acc[c]
            + DTf*(nacc[c]*DVf*A.nu + fo*gsh[x])*vmr;
    A.Kout[(size_t)r*NXC + x] = y;
  }
}

// ---------------- L step v3: 32-col tiles, 2 blocks/CU, broadcast reads ----------------
struct LArg { const float *V, *S2, *ED, *XD, *Xng; float nu, Amax; float* Lout; };
__global__ __launch_bounds__(256) void k_lstepf(LArg l0, LArg l1)
{
  LArg A = blockIdx.y ? l1 : l0;
  __shared__ float Lt[64*34];
  __shared__ float Mv[4*4160];
  __shared__ float xngs[64];
  float* S2l = Mv;                // slot0 [phase 0-1]
  float* Vt  = Mv + 4160;         // slot1: V tile 64x34 [phase 0-1]
  int v0 = blockIdx.x*32;
  int tid = threadIdx.x;
  // phase 0: stage S2, V tile, Ep->slot2, Em->slot3, xng
  for (int i=tid;i<4096;i+=256) S2l[(i>>6)*65+(i&63)] = A.S2[i];
  for (int i=tid;i<64*34;i+=256){
    int r=i/34, cc=i%34; int vv = v0-1+cc;
    Vt[i] = (vv>=0 && vv<NVC)? A.V[(size_t)r*NVC+vv] : 0.f;
  }
  {
    const float* Ep = A.ED; const float* Em = A.ED+4096;
    for (int i=tid;i<4096;i+=256){
      int r=i>>6,c=i&63;
      Mv[2*4160 + r*65+c] = Ep[i];
      Mv[3*4160 + r*65+c] = Em[i];
    }
  }
  if (tid<64) xngs[tid]=A.Xng[tid];
  __syncthreads();
  // phase 1: Lt[r][cc] = sum_q S2[r][q]*V[q][cc]
  for (int i=tid;i<64*34;i+=256){
    int r=i/34, cc=i%34;
    float a=0.f;
    for (int q=0;q<64;q++) a += S2l[r*65+q]*Vt[q*34+cc];
    Lt[i]=a;
  }
  __syncthreads();
  // phase 2: overwrite slot0/1 with G, H
  {
    const float* G = A.XD; const float* H = A.XD+4096;
    for (int i=tid;i<4096;i+=256){
      int r=i>>6,c=i&63;
      Mv[0*4160 + r*65+c]=G[i];
      Mv[1*4160 + r*65+c]=H[i];
    }
  }
  __syncthreads();
  // phase 3
  int r = tid & 63, w8 = (tid>>6)*8;
  const float DTDV = DTf/DVf;
  float fm = sqrtf(A.Amax*INV2PI);
  float acc[8], vpc[8], vmc[8], mvv[8];
  #pragma unroll
  for (int c=0;c<8;c++){
    int vgl = v0 + w8 + c;
    float vs = -VMAXf + (vgl+0.5f)*DVf;
    vpc[c] = vs>0.f?vs:0.f; vmc[c] = vs<0.f?vs:0.f;
    mvv[c] = fm*expf(-0.5f*A.Amax*vs*vs);
    acc[c] = 0.f;
  }
  for (int q=0;q<64;q++){
    float g  = Mv[0*4160 + r*65+q];
    float h  = Mv[1*4160 + r*65+q];
    float ht = Mv[1*4160 + q*65+r];
    float ep = Mv[2*4160 + r*65+q];
    float em = Mv[3*4160 + r*65+q];
    float gh = DTf*(g-h), hg = DTf*(ht-g);
    float dep = DTDV*ep, dem = DTDV*em;
    float b0 = -DTf*A.nu*DXf*g - (dep - dem);
    float lseg[10];
    #pragma unroll
    for (int c=0;c<10;c++) lseg[c] = Lt[q*34 + w8 + c];
    #pragma unroll
    for (int c=0;c<8;c++){
      float t = b0 - (vpc[c]*gh + vmc[c]*hg);
      acc[c] += t*lseg[c+1] + dep*lseg[c] - dem*lseg[c+2];
    }
  }
  float xr = xngs[r];
  #pragma unroll
  for (int c=0;c<8;c++){
    int vgl = v0 + w8 + c;
    float y = Lt[r*34 + w8 + c + 1] + acc[c] + DTf*xr*mvv[c];
    A.Lout[(size_t)r*NVC + vgl] = y;
  }
}

// ---------------- S step ----------------
struct SArgs {
  const float *S, *XD, *ED, *VD, *Vl, *Vr, *avec;
  float *S2;
  float nu;
};
__global__ __launch_bounds__(256) void k_sstep(SArgs ea, SArgs ia, const float* __restrict__ fluxg){
  SArgs A = (blockIdx.x==0)? ea : ia;
  const float* G = A.XD; const float* H = A.XD+4096; const float* XG = A.XD+8192;
  const float* Ep = A.ED; const float* Em = A.ED+4096;
  const float* vpm = A.VD+8192; const float* vmm = A.VD+12288; const float* VMv = A.VD+16448;
  __shared__ float Sl[64*65];
  __shared__ float Tt[64*65];
  __shared__ float ACC[64*65];
  __shared__ float xng[64];
  int tid = threadIdx.x;
  for (int i=tid;i<4096;i+=256) Sl[(i>>6)*65+(i&63)] = A.S[i];
  __syncthreads();
  for (int i=tid;i<4096;i+=256){
    int a=i>>6,b=i&63; float s=0.f;
    for (int c=0;c<64;c++) s += (G[a*64+c]-H[a*64+c])*Sl[c*65+b];
    Tt[a*65+b]=s;
  }
  __syncthreads();
  for (int i=tid;i<4096;i+=256){
    int a=i>>6,b=i&63; float s=0.f;
    for (int c=0;c<64;c++) s += Tt[a*65+c]*vpm[c*64+b];
    ACC[a*65+b]=s;
  }
  __syncthreads();
  for (int i=tid;i<4096;i+=256){
    int a=i>>6,b=i&63; float s=0.f;
    for (int c=0;c<64;c++) s += (H[c*64+a]-G[a*64+c])*Sl[c*65+b];
    Tt[a*65+b]=s;
  }
  __syncthreads();
  for (int i=tid;i<4096;i+=256){
    int a=i>>6,b=i&63; float s=0.f;
    for (int c=0;c<64;c++) s += Tt[a*65+c]*vmm[c*64+b];
    ACC[a*65+b]+=s;
  }
  __syncthreads();
  for (int i=tid;i<4096;i+=256){
    int a=i>>6,b=i&63; float s=0.f;
    for (int c=0;c<64;c++) s += Ep[a*64+c]*Sl[c*65+b];
    Tt[a*65+b]=s;
  }
  __syncthreads();
  for (int i=tid;i<4096;i+=256){
    int a=i>>6,b=i&63; float s=0.f;
    for (int c=0;c<64;c++) s += Tt[a*65+c]*A.Vl[b*64+c];
    ACC[a*65+b]+=s;
  }
  __syncthreads();
  for (int i=tid;i<4096;i+=256){
    int a=i>>6,b=i&63; float s=0.f;
    for (int c=0;c<64;c++) s += Em[a*64+c]*Sl[c*65+b];
    Tt[a*65+b]=s;
  }
  __syncthreads();
  for (int i=tid;i<4096;i+=256){
    int a=i>>6,b=i&63; float s=0.f;
    for (int c=0;c<64;c++) s += Tt[a*65+c]*A.Vr[b*64+c];
    ACC[a*65+b]+=s;
  }
  if (tid<64){
    float y=0.f;
    for (int q=0;q<64;q++) y += G[tid*64+q]*A.avec[q];
    xng[tid] = A.nu*DXf*DVf*y + fluxg[1]*XG[tid];
  }
  __syncthreads();
  for (int i=tid;i<4096;i+=256){
    int a=i>>6,b=i&63; float s=0.f;
    for (int c=0;c<64;c++) s += G[a*64+c]*Sl[c*65+b];
    float accv = ACC[a*65+b] + A.nu*DXf*s - xng[a]*VMv[b];
    A.S2[i] = A.S[i] + DTf*accv;
  }
}

// ---------------- Gram (fused, fp64 partials) ----------------
__global__ __launch_bounds__(256) void k_gramf(const float* __restrict__ A0, const float* __restrict__ A1,
                                               int n, double* __restrict__ part){
  __shared__ float At[64][65];
  int sp = blockIdx.y;
  const float* A = sp ? A1 : A0;
  int blk = blockIdx.x, nb = gridDim.x;
  int chunk = n/nb;
  int c0b = blk*chunk;
  int tid=threadIdx.x, ta=tid>>4, tb=tid&15, a0=ta*4, b0=tb*4;
  double acc[4][4];
  #pragma unroll
  for (int ka=0;ka<4;ka++){
    #pragma unroll
    for (int kb=0;kb<4;kb++) acc[ka][kb]=0.0;
  }
  for (int t0=0;t0<chunk;t0+=64){
    int c0=c0b+t0;
    for (int i=tid;i<64*64;i+=256){ int r=i>>6, cc=i&63; At[r][cc]=A[(size_t)r*n + c0+cc]; }
    __syncthreads();
    for (int cc=0;cc<64;cc++){
      float av[4],bv[4];
      #pragma unroll
      for(int k=0;k<4;k++){ av[k]=At[a0+k][cc]; bv[k]=At[b0+k][cc]; }
      #pragma unroll
      for(int ka=0;ka<4;ka++){
        #pragma unroll
        for(int kb=0;kb<4;kb++) acc[ka][kb] += (double)av[ka]*(double)bv[kb];
      }
    }
    __syncthreads();
  }
  double* pb = part + (size_t)(sp*nb+blk)*4096;
  #pragma unroll
  for(int ka=0;ka<4;ka++){
    #pragma unroll
    for(int kb=0;kb<4;kb++) pb[(a0+ka)*64 + b0+kb] = acc[ka][kb];
  }
}

// ---------------- blocked fp32 Cholesky (upper, 64x64, stride-65), NB=8, BD=512 ----------------
__device__ void chol_blk32(float* __restrict__ M, int tid){
  for (int p=0;p<8;p++){
    const int b=8*p;
    if (tid<64){
      float st[8];
      #pragma unroll
      for (int j=0;j<8;j++) st[j] = M[(b+j)*65 + tid];
      #pragma unroll
      for (int kk=0;kk<8;kk++){
        float q[8];
        #pragma unroll
        for (int j=0;j<8;j++) q[j] = __shfl(st[kk], b+j, 64);
        float d = q[kk];
        float rinv = (d > 0.f) ? 1.f/d : 0.f;
        float sk = st[kk];
        #pragma unroll
        for (int j=0;j<8;j++) if (j>kk) st[j] -= q[j]*sk*rinv;
        st[kk] = sk * ((d > 0.f)? rsqrtf(d) : 0.f);
      }
      #pragma unroll
      for (int j=0;j<8;j++) M[(b+j)*65 + tid] = st[j];
    }
    __syncthreads();
    if (b+8 < 64){
      for (int i=(b+8)*64 + tid; i<4096; i+=512){
        int r=i>>6, c=i&63;
        if (c>=r){
          float s=0.f;
          #pragma unroll
          for (int j=0;j<8;j++) s += M[(b+j)*65+r]*M[(b+j)*65+c];
          M[r*65+c] -= s;
        }
      }
    }
    __syncthreads();
  }
}

// ---------------- fused QR v3: fp32, 512 threads ----------------
struct QArgs {
  const double* Gd; const float* A; int n;
  float scaleS, invQ;
  float* SolveM; float* Sout; int outPitch; int mode;
};
__global__ __launch_bounds__(512) void k_qr(QArgs q0, QArgs q1){
  QArgs Q = (blockIdx.x==0)? q0 : q1;
  __shared__ float Lg[64*65];
  __shared__ float Lw[64*65];
  __shared__ float Atf[64*65];
  __shared__ float Cf[64*65];
  __shared__ float Vp[8*129];
  __shared__ float TmpI[448];
  __shared__ float Dd[64], Tm[64], vvs[8], tauv[8], Dv[64];
  int tid = threadIdx.x;
  for (int i=tid;i<4096;i+=512) Lg[(i>>6)*65 + (i&63)] = (float)Q.Gd[i];
  for (int i=tid;i<4096;i+=512){ int c=i>>6,x=i&63; Atf[c*65+x] = Q.A[(size_t)c*Q.n + x]; }
  __syncthreads();
  chol_blk32(Lg, tid);
  for (int i=tid;i<4096;i+=512){
    int r=i>>6, c=i&63;
    double s = Q.Gd[i];
    for (int x=0;x<64;x++) s -= (double)Atf[r*65+x]*(double)Atf[c*65+x];
    Cf[r*65+c] = (float)s;
  }
  __syncthreads();
  chol_blk32(Cf, tid);
  if (tid<64){
    int p=tid>>3, cc=tid&7, b=8*p;
    float wcol[8];
    #pragma unroll
    for (int r=7;r>=0;r--){
      float s = (r==cc)? 1.f : 0.f;
      #pragma unroll
      for (int j=0;j<8;j++) if (j>r) s -= Lg[(b+r)*65 + (b+j)]*wcol[j];
      float dg = Lg[(b+r)*65 + (b+r)];
      wcol[r] = (r<=cc && dg!=0.f)? s/dg : 0.f;
    }
    #pragma unroll
    for (int r=0;r<8;r++) Lw[(b+r)*65 + (b+cc)] = wcol[r];
  }
  __syncthreads();
  for (int d=1; d<8; d++){
    int nb2 = 8-d;
    if (tid < nb2*64){
      int bb=tid>>6, rc=tid&63, r=rc>>3, c=rc&7;
      int p=bb, qb=p+d;
      float s=0.f;
      for (int m=p+1;m<=qb;m++){
        #pragma unroll
        for (int jj=0;jj<8;jj++)
          s += Lg[(8*p+r)*65 + 8*m+jj]*Lw[(8*m+jj)*65 + 8*qb+c];
      }
      TmpI[tid]=s;
    }
    __syncthreads();
    if (tid < nb2*64){
      int bb=tid>>6, rc=tid&63, r=rc>>3, c=rc&7;
      int p=bb, qb=p+d;
      float s=0.f;
      #pragma unroll
      for (int rr=0;rr<8;rr++)
        s += Lw[(8*p+r)*65 + 8*p+rr]*TmpI[(bb<<6)+(rr<<3)+c];
      Lw[(8*p+r)*65 + 8*qb+c] = -s;
    }
    __syncthreads();
  }
  int col = tid>>3, l8 = tid&7;
  float a[16];
  #pragma unroll
  for (int j=0;j<16;j++){
    int row = l8 + 8*j;
    if (row < 64) a[j] = Atf[col*65 + row];
    else { int r = row - 64; a[j] = (col>=r)? Cf[r*65+col] : 0.f; }
  }
  for (int p8=0;p8<8;p8++){
    const int b = 8*p8;
    if (col>=b && col<b+8){
      #pragma unroll 1
      for (int kk=0;kk<8;kk++){
        int k = b+kk;
        float sg=0.f, al=0.f;
        #pragma unroll
        for (int j=0;j<16;j++){
          int row = l8 + 8*j;
          float v = (row>=k)? a[j] : 0.f;
          sg += v*v;
          al += (row==k)? a[j] : 0.f;
        }
        sg += __shfl_xor(sg,1,64); sg += __shfl_xor(sg,2,64); sg += __shfl_xor(sg,4,64);
        al += __shfl_xor(al,1,64); al += __shfl_xor(al,2,64); al += __shfl_xor(al,4,64);
        float sgb = __shfl(sg, kk*8, 64);
        float alb = __shfl(al, kk*8, 64);
        float beta = (alb >= 0.f)? -sqrtf(sgb) : sqrtf(sgb);
        float vk = alb - beta;
        float vv = sgb - alb*beta;
        if (col==k){
          #pragma unroll
          for (int j=0;j<16;j++){
            int row = l8 + 8*j;
            a[j] = (row<k)? 0.f : ((row==k)? vk : a[j]);
          }
          #pragma unroll
          for (int j=0;j<16;j++) Vp[kk*129 + l8 + 8*j] = a[j];
          if (l8==0){ Dv[k] = (beta >= 0.f)? 1.f : -1.f; vvs[kk] = vv; }
        }
        float vj[16]; float s=0.f;
        #pragma unroll
        for (int j=0;j<16;j++){ vj[j] = __shfl(a[j], kk*8 + l8, 64); s += vj[j]*a[j]; }
        s += __shfl_xor(s,1,64); s += __shfl_xor(s,2,64); s += __shfl_xor(s,4,64);
        if (col>k && vv > 0.f){
          float f = s/vv;
          #pragma unroll
          for (int j=0;j<16;j++) a[j] -= f*vj[j];
        }
      }
    }
    __syncthreads();
    {
      int pr = tid>>3, m = pr>>3, i2 = pr&7;
      float sd=0.f;
      #pragma unroll
      for (int j=0;j<16;j++){ int row = l8 + 8*j; sd += Vp[m*129+row]*Vp[i2*129+row]; }
      sd += __shfl_xor(sd,1,64); sd += __shfl_xor(sd,2,64); sd += __shfl_xor(sd,4,64);
      if (l8==0 && m<i2) Dd[m*8+i2]=sd;
      if (tid<8) tauv[tid] = (vvs[tid]>0.f)? 1.f/vvs[tid] : 0.f;
    }
    __syncthreads();
    if (tid<8){
      int j=tid;
      for (int i2=0;i2<8;i2++){
        if (i2==j) Tm[j*8+j]=tauv[j];
        else if (i2>j){
          float s2=0.f;
          for (int m=j;m<i2;m++) s2 += Tm[j*8+m]*Dd[m*8+i2];
          Tm[j*8+i2] = -tauv[i2]*s2;
        } else Tm[j*8+i2]=0.f;
      }
    }
    __syncthreads();
    if (col >= b+8){
      float z[8];
      #pragma unroll
      for (int kk=0;kk<8;kk++){
        float s2=0.f;
        #pragma unroll
        for (int j=0;j<16;j++){ int row = l8 + 8*j; s2 += Vp[kk*129+row]*a[j]; }
        s2 += __shfl_xor(s2,1,64); s2 += __shfl_xor(s2,2,64); s2 += __shfl_xor(s2,4,64);
        z[kk]=s2;
      }
      float y[8];
      #pragma unroll
      for (int kk=0;kk<8;kk++){
        float s2=0.f;
        #pragma unroll
        for (int m=0;m<8;m++) if (m<=kk) s2 += Tm[m*8+kk]*z[m];
        y[kk]=s2;
      }
      #pragma unroll
      for (int j=0;j<16;j++){
        int row = l8 + 8*j;
        float s2=0.f;
        #pragma unroll
        for (int kk=0;kk<8;kk++) s2 += Vp[kk*129+row]*y[kk];
        a[j] -= s2;
      }
    }
    __syncthreads();
  }
  for (int i=tid;i<4096;i+=512){
    int r=i>>6, q2=i&63;
    Q.SolveM[i] = (q2<=r)? (Dv[r]*Lw[q2*65+r]*Q.invQ) : 0.f;
    if (Q.mode==0){
      Q.Sout[i] = (q2>=r)? (Dv[r]*Lg[r*65+q2]*Q.scaleS) : 0.f;
    } else {
      Q.Sout[(size_t)r*Q.outPitch + q2] = (r>=q2)? (Dv[q2]*Lg[q2*65+r]*Q.scaleS) : 0.f;
    }
  }
}

// ---------------- Q formation (fused species) ----------------
__global__ __launch_bounds__(256) void k_qformf(const float* __restrict__ A0, const float* __restrict__ A1,
    int n, const float* __restrict__ M0, const float* __restrict__ M1,
    float* __restrict__ O0, float* __restrict__ O1, int pitch)
{
  int sp = blockIdx.y >> 2;
  const float* A = sp ? A1 : A0;
  const float* M = sp ? M1 : M0;
  float* Out = sp ? O1 : O0;
  int x = blockIdx.x*256 + threadIdx.x;
  int r0 = (blockIdx.y & 3)*16;
  float acc[16];
  #pragma unroll
  for (int rr=0;rr<16;rr++) acc[rr]=0.f;
  for (int q=0;q<64;q++){
    float aq = A[(size_t)q*n + x];
    #pragma unroll
    for (int rr=0;rr<16;rr++) acc[rr] += M[(r0+rr)*64 + q]*aq;
  }
  #pragma unroll
  for (int rr=0;rr<16;rr++) Out[(size_t)(r0+rr)*pitch + x] = acc[rr];
}

// ======================= host =======================
extern "C" void kernel_launch(void* const* d_in, const int* in_sizes, int n_in,
                              void* d_out, int out_size, void* d_ws, size_t ws_size,
                              hipStream_t stream)
{
  (void)in_sizes; (void)n_in; (void)out_size; (void)ws_size;
  const float* Xe = (const float*)d_in[0];
  const float* Se = (const float*)d_in[1];
  const float* Ve = (const float*)d_in[2];
  const float* Xi = (const float*)d_in[3];
  const float* Si = (const float*)d_in[4];
  const float* Vi = (const float*)d_in[5];
  float* out = (float*)d_out;
  float* w = (float*)d_ws;

  size_t o = 0;
  auto alloc = [&](size_t nn){ size_t r=o; o += (nn+63)&~(size_t)63; return r; };
  size_t F_VD = alloc(2*PS_V);
  size_t F_XD = alloc(2*PS_X);
  size_t F_ED = alloc(2*PS_E);
  size_t F_VL_E = alloc(4096), F_VR_E = alloc(4096), F_VL_I = alloc(4096), F_VR_I = alloc(4096);
  size_t F_SC_E = alloc(4096), F_SC_I = alloc(4096), F_S2_E = alloc(4096), F_S2_I = alloc(4096);
  size_t F_SOLVE_E = alloc(4096), F_SOLVE_I = alloc(4096);
  size_t F_AE = alloc(64), F_AI = alloc(64), F_XNGE = alloc(64), F_XNGI = alloc(64);
  size_t F_FLUX = alloc(64);
  size_t F_GSH = alloc(NXC);
  size_t F_RHO = alloc(NXC);
  size_t F_E   = alloc(NXC);
  size_t F_KE = alloc((size_t)64*NXC);
  size_t F_KI = alloc((size_t)64*NXC);
  size_t F_LE = F_KE;
  size_t F_LI = F_KI;
  size_t F_PART = alloc(1060864);
  size_t F_GQR = alloc(16384);   // 8192 doubles (2 species)
  double* Gqr = (double*)(w + F_GQR);
  double* partd = (double*)(w + F_PART);
  float* part = w + F_PART;
  float* vpart = w + F_KE;       // vstats partials live in (dead) K region: 64*2*PS_V floats
  const float* VDe = w + F_VD;
  const float* VDi = w + F_VD + PS_V;
  const float* XDe = w + F_XD;
  const float* XDi = w + F_XD + PS_X;
  const float* EDe = w + F_ED;
  const float* EDi = w + F_ED + PS_E;

  float sqDX = sqrtf(DXf), isqDX = 1.f/sqrtf(DXf);
  float sqDV = sqrtf(DVf), isqDV = 1.f/sqrtf(DVf);
  const float NUE = 1.0f, NUI = 0.04f;
  const float FACE = -1.0f, FACI = 1.0f/1836.0f;

  // --- V-derived stats ---
  k_vstatsf<<<dim3(64,2),256,0,stream>>>(Ve, Vi, vpart);
  k_reduce32f<<<dim3((PS_V+255)/256,2),256,0,stream>>>(vpart, 64, PS_V, w+F_VD);
  k_gshape<<<1,1024,0,stream>>>(w+F_GSH);
  k_prep1<<<1,256,0,stream>>>(Ve, Vi, Se, Si, Xi, VDe, VDi,
                              w+F_VL_E, w+F_VR_E, w+F_VL_I, w+F_VR_I,
                              w+F_AE, w+F_AI, w+F_FLUX);
  // --- K step ---
  k_rho<<<NXC/256,256,0,stream>>>(Xe, NXC, Xi, NXC, w+F_AE, w+F_AI, w+F_RHO);
  k_poisson<<<1,1024,0,stream>>>(w+F_RHO, w+F_E);
  KArg ke{Xe, Se, VDe, w+F_VL_E, w+F_VR_E, NUE, FACE, w+F_KE};
  KArg ki{Xi, Si, VDi, w+F_VL_I, w+F_VR_I, NUI, FACI, w+F_KI};
  k_kstepf<<<dim3(NXC/32,2),256,0,stream>>>(ke, ki, w+F_E, w+F_GSH, w+F_FLUX);
  // --- QR of K^T (both species) ---
  k_gramf<<<dim3(64,2),256,0,stream>>>(w+F_KE, w+F_KI, NXC, partd);
  k_reduce64f<<<dim3(16,2),256,0,stream>>>(partd, 64, Gqr);
  {
    QArgs qe{Gqr,        w+F_KE, NXC, sqDX, isqDX, w+F_SOLVE_E, w+F_SC_E, 0, 0};
    QArgs qi{Gqr+4096,   w+F_KI, NXC, sqDX, isqDX, w+F_SOLVE_I, w+F_SC_I, 0, 0};
    k_qr<<<2,512,0,stream>>>(qe, qi);
  }
  k_qformf<<<dim3(NXC/256,8),256,0,stream>>>(w+F_KE, w+F_KI, NXC, w+F_SOLVE_E, w+F_SOLVE_I,
                                             out, out + (size_t)64*OUTWC, OUTWC);
  // --- X stats on new X ---
  k_xstatsf<<<dim3(64,2),256,0,stream>>>(out, out + (size_t)64*OUTWC, OUTWC, w+F_GSH, part);
  k_reduce32f<<<dim3((PS_X+255)/256,2),256,0,stream>>>(part, 64, PS_X, w+F_XD);
  // --- S step ---
  k_prep2<<<1,256,0,stream>>>(w+F_SC_E, w+F_SC_I, VDe, VDi, out + (size_t)64*OUTWC,
                              w+F_AE, w+F_AI, w+F_FLUX);
  k_rho<<<NXC/256,256,0,stream>>>(out, OUTWC, out + (size_t)64*OUTWC, OUTWC, w+F_AE, w+F_AI, w+F_RHO);
  k_poisson<<<1,1024,0,stream>>>(w+F_RHO, w+F_E);
  k_eweightf<<<dim3(64,2),256,0,stream>>>(out, out + (size_t)64*OUTWC, OUTWC, w+F_E, FACE, FACI, part);
  k_reduce32f<<<dim3((PS_E+255)/256,2),256,0,stream>>>(part, 64, PS_E, w+F_ED);
  SArgs ea; ea.S=w+F_SC_E; ea.XD=XDe; ea.ED=EDe; ea.VD=VDe; ea.Vl=w+F_VL_E; ea.Vr=w+F_VR_E; ea.avec=w+F_AE; ea.S2=w+F_S2_E; ea.nu=NUE;
  SArgs ia; ia.S=w+F_SC_I; ia.XD=XDi; ia.ED=EDi; ia.VD=VDi; ia.Vl=w+F_VL_I; ia.Vr=w+F_VR_I; ia.avec=w+F_AI; ia.S2=w+F_S2_I; ia.nu=NUI;
  k_sstep<<<2,256,0,stream>>>(ea, ia, w+F_FLUX);
  // --- L step ---
  k_prep3<<<1,256,0,stream>>>(w+F_S2_E, w+F_S2_I, VDe, VDi, out + (size_t)64*OUTWC,
                              XDe, XDi, w+F_AE, w+F_AI, w+F_XNGE, w+F_XNGI, w+F_FLUX);
  k_rho<<<NXC/256,256,0,stream>>>(out, OUTWC, out + (size_t)64*OUTWC, OUTWC, w+F_AE, w+F_AI, w+F_RHO);
  k_poisson<<<1,1024,0,stream>>>(w+F_RHO, w+F_E);
  k_eweightf<<<dim3(64,2),256,0,stream>>>(out, out + (size_t)64*OUTWC, OUTWC, w+F_E, FACE, FACI, part);
  k_reduce32f<<<dim3((PS_E+255)/256,2),256,0,stream>>>(part, 64, PS_E, w+F_ED);
  LArg le{Ve, w+F_S2_E, EDe, XDe, w+F_XNGE, NUE, 1.0f,    w+F_LE};
  LArg li{Vi, w+F_S2_I, EDi, XDi, w+F_XNGI, NUI, 1836.0f, w+F_LI};
  k_lstepf<<<dim3(NVC/32,2),256,0,stream>>>(le, li);
  // --- QR of L^T (both species) ---
  k_gramf<<<dim3(64,2),256,0,stream>>>(w+F_LE, w+F_LI, NVC, partd);
  k_reduce64f<<<dim3(16,2),256,0,stream>>>(partd, 64, Gqr);
  {
    QArgs qe{Gqr,      w+F_LE, NVC, sqDV, isqDV, w+F_SOLVE_E, out + NXC,                        OUTWC, 1};
    QArgs qi{Gqr+4096, w+F_LI, NVC, sqDV, isqDV, w+F_SOLVE_I, out + (size_t)64*OUTWC + NXC,     OUTWC, 1};
    k_qr<<<2,512,0,stream>>>(qe, qi);
  }
  k_qformf<<<dim3(NVC/256,8),256,0,stream>>>(w+F_LE, w+F_LI, NVC, w+F_SOLVE_E, w+F_SOLVE_I,
                                             out + NXC + 64, out + (size_t)64*OUTWC + NXC + 64, OUTWC);
}